// Round 8
// baseline (181.276 us; speedup 1.0000x reference)
//
#include <hip/hip_runtime.h>

// ---------------- problem constants ----------------
#define BB   8
#define KQ   64
#define HDIM 2048
#define NH   16
#define NKV  4
#define HD   128
#define CTX  4096
#define TTOT 4160      // CTX + KQ
#define NTILES 65      // TTOT / 64
#define LOG2E 1.4426950408889634f
#define SCALE 0.08838834764831845f  // 1/sqrt(128)
#define QSCALE (SCALE * LOG2E)      // folded into Q; exp2-domain softmax
// |q.k| <= 128 after RMS-norm => |sc| <= 128*QSCALE = 16.33. Fixed softmax max.
#define MFIX 16.34f

typedef unsigned short u16;
typedef unsigned int   u32;
typedef __attribute__((ext_vector_type(8))) short  s16x8;   // bf16 storage
typedef __attribute__((ext_vector_type(4))) unsigned short u16x4;
typedef __attribute__((ext_vector_type(4))) float  f32x4;
typedef __bf16 bf16x8 __attribute__((ext_vector_type(8)));  // MFMA operand

__device__ __forceinline__ u16 f2bf(float f) {              // HW RNE cvt
    union { __bf16 h; u16 u; } v; v.h = (__bf16)f; return v.u;
}
__device__ __forceinline__ float bf2f(u16 u) {
    union { float f; u32 u; } v; v.u = ((u32)u) << 16;
    return v.f;
}
__device__ __forceinline__ u32 pack2(float a, float b) {
    return (u32)f2bf(a) | ((u32)f2bf(b) << 16);
}
__device__ __forceinline__ f32x4 mfma16(bf16x8 a, bf16x8 b, f32x4 c) {
    return __builtin_amdgcn_mfma_f32_16x16x32_bf16(a, b, c, 0, 0, 0);
}

// ---------------- 64x64-tile GEMM core (padded LDS, reg prefetch) ---------
// 256 threads = 4 waves, wave = 32x32 sub-tile, BK=64.
// Round-7 lesson: prefetch IS issued early (VGPR 48 = 32 dest + 16 acc), but
// per-iter compute (~300cy) < load latency (~600-900cy) and 1.5 blk/CU gave
// no TLP to cover the residual. Fix = split-K grid (6 blk/CU), not regs.
__device__ __forceinline__ void gemm64_body(
    const float* __restrict__ Ab, const float* __restrict__ Bb,
    float* __restrict__ Cb, const int ldc, const int ldk, const int Klen,
    u16* Ash, u16* Bsh)
{
    const int tid = threadIdx.x, lane = tid & 63;
    const int w = tid >> 6, wm = w >> 1, wn = w & 1;
    const int l15 = lane & 15, l4 = lane >> 4;
    const int srow = tid >> 2, scol = (tid & 3) * 16;

    f32x4 acc[2][2];
#pragma unroll
    for (int i = 0; i < 2; ++i)
#pragma unroll
        for (int j = 0; j < 2; ++j) acc[i][j] = (f32x4){0.f, 0.f, 0.f, 0.f};

    const float* ap = Ab + (size_t)srow * ldk + scol;
    const float* bp = Bb + (size_t)srow * ldk + scol;
    float4 ra0 = *(const float4*)ap,       ra1 = *(const float4*)(ap + 4);
    float4 ra2 = *(const float4*)(ap + 8), ra3 = *(const float4*)(ap + 12);
    float4 rb0 = *(const float4*)bp,       rb1 = *(const float4*)(bp + 4);
    float4 rb2 = *(const float4*)(bp + 8), rb3 = *(const float4*)(bp + 12);
    __builtin_amdgcn_sched_barrier(0);

    for (int k0 = 0; k0 < Klen; k0 += 64) {
        __syncthreads();
        {
            s16x8 av0, av1, bv0, bv1;
            av0[0]=(short)f2bf(ra0.x); av0[1]=(short)f2bf(ra0.y); av0[2]=(short)f2bf(ra0.z); av0[3]=(short)f2bf(ra0.w);
            av0[4]=(short)f2bf(ra1.x); av0[5]=(short)f2bf(ra1.y); av0[6]=(short)f2bf(ra1.z); av0[7]=(short)f2bf(ra1.w);
            av1[0]=(short)f2bf(ra2.x); av1[1]=(short)f2bf(ra2.y); av1[2]=(short)f2bf(ra2.z); av1[3]=(short)f2bf(ra2.w);
            av1[4]=(short)f2bf(ra3.x); av1[5]=(short)f2bf(ra3.y); av1[6]=(short)f2bf(ra3.z); av1[7]=(short)f2bf(ra3.w);
            bv0[0]=(short)f2bf(rb0.x); bv0[1]=(short)f2bf(rb0.y); bv0[2]=(short)f2bf(rb0.z); bv0[3]=(short)f2bf(rb0.w);
            bv0[4]=(short)f2bf(rb1.x); bv0[5]=(short)f2bf(rb1.y); bv0[6]=(short)f2bf(rb1.z); bv0[7]=(short)f2bf(rb1.w);
            bv1[0]=(short)f2bf(rb2.x); bv1[1]=(short)f2bf(rb2.y); bv1[2]=(short)f2bf(rb2.z); bv1[3]=(short)f2bf(rb2.w);
            bv1[4]=(short)f2bf(rb3.x); bv1[5]=(short)f2bf(rb3.y); bv1[6]=(short)f2bf(rb3.z); bv1[7]=(short)f2bf(rb3.w);
            *(s16x8*)(Ash + srow * 72 + scol)     = av0;
            *(s16x8*)(Ash + srow * 72 + scol + 8) = av1;
            *(s16x8*)(Bsh + srow * 72 + scol)     = bv0;
            *(s16x8*)(Bsh + srow * 72 + scol + 8) = bv1;
        }
        __syncthreads();
        if (k0 + 64 < Klen) {
            const float* ap2 = ap + k0 + 64;
            const float* bp2 = bp + k0 + 64;
            ra0 = *(const float4*)ap2;       ra1 = *(const float4*)(ap2 + 4);
            ra2 = *(const float4*)(ap2 + 8); ra3 = *(const float4*)(ap2 + 12);
            rb0 = *(const float4*)bp2;       rb1 = *(const float4*)(bp2 + 4);
            rb2 = *(const float4*)(bp2 + 8); rb3 = *(const float4*)(bp2 + 12);
            __builtin_amdgcn_sched_barrier(0);
        }
#pragma unroll
        for (int ks = 0; ks < 2; ++ks) {
            bf16x8 am[2], bb[2];
#pragma unroll
            for (int i = 0; i < 2; ++i) {
                am[i] = *(const bf16x8*)(Ash + (wm * 32 + i * 16 + l15) * 72 + ks * 32 + l4 * 8);
                bb[i] = *(const bf16x8*)(Bsh + (wn * 32 + i * 16 + l15) * 72 + ks * 32 + l4 * 8);
            }
#pragma unroll
            for (int i = 0; i < 2; ++i)
#pragma unroll
                for (int j = 0; j < 2; ++j)
                    acc[i][j] = mfma16(am[i], bb[j], acc[i][j]);
        }
    }

    float* Cw = Cb + (size_t)(wm * 32) * ldc + wn * 32;
#pragma unroll
    for (int i = 0; i < 2; ++i)
#pragma unroll
        for (int j = 0; j < 2; ++j)
#pragma unroll
            for (int r = 0; r < 4; ++r)
                Cw[(size_t)(i * 16 + l4 * 4 + r) * ldc + j * 16 + l15] = acc[i][j][r];
}

// QKV projection, split-K: grid (8, 48, KS). Partials to qkvp[kc][512][3072].
template <int KS>
__global__ __launch_bounds__(256) void gemm_qkv_sk(
    const float* __restrict__ hs, const float* __restrict__ wq,
    const float* __restrict__ wk, const float* __restrict__ wv,
    float* __restrict__ qkvp)
{
    __shared__ __align__(16) u16 Ash[64 * 72];
    __shared__ __align__(16) u16 Bsh[64 * 72];
    const int by = blockIdx.y, kc = blockIdx.z;
    const int koff = kc * (HDIM / KS);
    const float* Bt;
    if (by < 32)      Bt = wq + (size_t)by * 64 * HDIM;
    else if (by < 40) Bt = wk + (size_t)(by - 32) * 64 * HDIM;
    else              Bt = wv + (size_t)(by - 40) * 64 * HDIM;
    const float* Ab = hs + (size_t)blockIdx.x * 64 * HDIM;
    float* Cb = qkvp + (size_t)kc * 512 * 3072 + (size_t)blockIdx.x * 64 * 3072 + by * 64;
    gemm64_body(Ab + koff, Bt + koff, Cb, 3072, HDIM, HDIM / KS, Ash, Bsh);
}

// generic split-K: grid (M/64, N/64, KS); partials Cp[kc][M][N].
template <int KS>
__global__ __launch_bounds__(256) void gemm64_sk(
    const float* __restrict__ A, const float* __restrict__ Bt,
    float* __restrict__ Cp, const int M, const int N, const int Kd)
{
    __shared__ __align__(16) u16 Ash[64 * 72];
    __shared__ __align__(16) u16 Bsh[64 * 72];
    const int kc = blockIdx.z;
    const int koff = kc * (Kd / KS);
    const float* Ab = A + (size_t)blockIdx.x * 64 * Kd + koff;
    const float* Bb = Bt + (size_t)blockIdx.y * 64 * Kd + koff;
    float* Cb = Cp + (size_t)kc * M * N + (size_t)blockIdx.x * 64 * N + blockIdx.y * 64;
    gemm64_body(Ab, Bb, Cb, N, Kd, Kd / KS, Ash, Bsh);
}

// sum 4 partial chunks -> out (float4 per thread), deterministic.
__global__ __launch_bounds__(256) void reduce4(
    const float* __restrict__ p, float* __restrict__ out, const size_t chunk)
{
    const size_t i = ((size_t)blockIdx.x * 256 + threadIdx.x) * 4;
    float4 a = *(const float4*)(p + i);
    float4 b = *(const float4*)(p + i + chunk);
    float4 c = *(const float4*)(p + i + 2 * chunk);
    float4 d = *(const float4*)(p + i + 3 * chunk);
    float4 r;
    r.x = (a.x + b.x) + (c.x + d.x);
    r.y = (a.y + b.y) + (c.y + d.y);
    r.z = (a.z + b.z) + (c.z + d.z);
    r.w = (a.w + b.w) + (c.w + d.w);
    *(float4*)(out + i) = r;
}

// ---------------- shared RMSNorm+RoPE helper (half-wave, float2-paired) ---
__device__ __forceinline__ void norm_rope_row(
    const float* __restrict__ src, const float* __restrict__ wgt,
    const float* __restrict__ cosT, const float* __restrict__ sinT,
    int pos, int j, float outScale, u16* __restrict__ dst)
{
    float2 xa = *(const float2*)(src + 2 * j);
    float2 xb = *(const float2*)(src + 2 * j + 64);
    float ss = xa.x * xa.x + xa.y * xa.y + xb.x * xb.x + xb.y * xb.y;
#pragma unroll
    for (int m = 1; m < 32; m <<= 1) ss += __shfl_xor(ss, m);
    const float rr = rsqrtf(ss * (1.0f / 128.0f) + 1e-6f);
    float2 wa = *(const float2*)(wgt + 2 * j);
    float2 wb = *(const float2*)(wgt + 2 * j + 64);
    const float* cp = cosT + (size_t)pos * 128;
    const float* sp = sinT + (size_t)pos * 128;
    float2 ca = *(const float2*)(cp + 2 * j), cb = *(const float2*)(cp + 2 * j + 64);
    float2 sa = *(const float2*)(sp + 2 * j), sb = *(const float2*)(sp + 2 * j + 64);
    const float nax = xa.x * rr * wa.x, nay = xa.y * rr * wa.y;
    const float nbx = xb.x * rr * wb.x, nby = xb.y * rr * wb.y;
    const float lox = (nax * ca.x - nbx * sa.x) * outScale;
    const float loy = (nay * ca.y - nby * sa.y) * outScale;
    const float hix = (nbx * cb.x + nax * sb.x) * outScale;
    const float hiy = (nby * cb.y + nay * sb.y) * outScale;
    ((u32*)dst)[j]      = pack2(lox, loy);
    ((u32*)dst)[j + 32] = pack2(hix, hiy);
}

__global__ __launch_bounds__(256) void finalize_q(
    const float* __restrict__ qkv, const float* __restrict__ qw,
    const float* __restrict__ cosT, const float* __restrict__ sinT, u16* __restrict__ Qb)
{
    const int unit = blockIdx.x * 8 + (threadIdx.x >> 5);   // bq*16 + h
    const int j = threadIdx.x & 31;
    const int bq = unit >> 4, h = unit & 15;
    const int b = bq >> 6, q = bq & 63;
    norm_rope_row(qkv + (size_t)bq * 3072 + h * 128, qw, cosT, sinT,
                  CTX + q, j, QSCALE,
                  Qb + ((size_t)((b * 16 + h) * 64 + q)) * 128);
}

__global__ __launch_bounds__(256) void build_k(
    const float* __restrict__ ctxk, const float* __restrict__ kw,
    const float* __restrict__ cosT, const float* __restrict__ sinT, u16* __restrict__ Kb)
{
    const int unit = blockIdx.x * 8 + (threadIdx.x >> 5);   // (b*4096+pos)*4 + kv
    const int j = threadIdx.x & 31;
    const int kv = unit & 3, rid = unit >> 2;
    const int b = rid >> 12, pos = rid & 4095;
    norm_rope_row(ctxk + ((size_t)rid * 4 + kv) * 128, kw, cosT, sinT,
                  pos, j, 1.0f,
                  Kb + ((size_t)(b * 4 + kv) * TTOT + pos) * 128);
}

__global__ __launch_bounds__(256) void build_vt(
    const float* __restrict__ ctxv, u16* __restrict__ VtG)
{
    const int pt = blockIdx.x, kv = blockIdx.y, b = blockIdx.z;
    const int t = threadIdx.x;
    const int d = t & 127, half = t >> 7;
    const int p0 = pt * 64 + half * 32;

    u16* dst = VtG + ((size_t)(b * 4 + kv) * 128 + d) * TTOT + p0;
    const float* src = ctxv + ((size_t)(b * 4096 + p0) * 4 + kv) * 128 + d;
#pragma unroll
    for (int j8 = 0; j8 < 4; ++j8) {
        s16x8 v;
#pragma unroll
        for (int je = 0; je < 8; ++je)
            v[je] = (short)f2bf(src[(size_t)(j8 * 8 + je) * 512]);
        *(s16x8*)(dst + j8 * 8) = v;
    }
}

__global__ __launch_bounds__(256) void build_noise(
    const float* __restrict__ qkv, const float* __restrict__ kw,
    const float* __restrict__ cosT, const float* __restrict__ sinT,
    u16* __restrict__ Kb, u16* __restrict__ VtG)
{
    const int unit = blockIdx.x * 8 + (threadIdx.x >> 5);   // bq*4 + kv
    const int j = threadIdx.x & 31;
    const int kv = unit & 3, bq = unit >> 2;
    const int b = bq >> 6, q = bq & 63;
    const int pos = CTX + q;

    norm_rope_row(qkv + (size_t)bq * 3072 + 2048 + kv * 128, kw, cosT, sinT,
                  pos, j, 1.0f,
                  Kb + ((size_t)(b * 4 + kv) * TTOT + pos) * 128);

    const float* vsrc = qkv + (size_t)bq * 3072 + 2560 + kv * 128;
    float2 va = *(const float2*)(vsrc + 2 * j);
    float2 vb = *(const float2*)(vsrc + 2 * j + 64);
    u16* vt = VtG + (size_t)(b * 4 + kv) * 128 * TTOT;
    vt[(size_t)(2 * j) * TTOT + pos]      = f2bf(va.x);
    vt[(size_t)(2 * j + 1) * TTOT + pos]  = f2bf(va.y);
    vt[(size_t)(2 * j + 64) * TTOT + pos] = f2bf(vb.x);
    vt[(size_t)(2 * j + 65) * TTOT + pos] = f2bf(vb.y);
}

// ---------------- flash attention partial: pipelined double-buffer --------
// (round-6 proven: 1 block/CU, LDS 124 KB, loads never in flight at barrier)
template <int S>
__global__ __launch_bounds__(512, 2) void attn_partial(
    const u16* __restrict__ Qb, const u16* __restrict__ Kb, const u16* __restrict__ VtG,
    const float* __restrict__ mask, u16* __restrict__ Opart, float* __restrict__ lsum)
{
    __shared__ __align__(16) u16   Ksh[2][64 * 136];   // K [pos][d], padded
    __shared__ __align__(16) u16   Vsh[2][128 * 72];   // V^T [d][pos], padded
    __shared__ __align__(16) float Msh[2][64 * 68];    // mask*log2e - MFIX
    __shared__ __align__(16) u16   Psh[8][32 * 40];    // per-wave P chunk

    const int s = blockIdx.x, kv = blockIdx.y, b = blockIdx.z;
    const int tid = threadIdx.x, lane = tid & 63, w = tid >> 6;
    const int h = kv * 4 + (w >> 1);
    const int qh = w & 1, qbase = qh * 32;
    const int l15 = lane & 15, l4 = lane >> 4;
    const int t0 = (NTILES * s) / S, t1 = (NTILES * (s + 1)) / S;

    bf16x8 aq[2][4];
    {
        const u16* qb = Qb + ((size_t)((b * 16 + h) * 64 + qbase)) * 128;
#pragma unroll
        for (int mt = 0; mt < 2; ++mt)
#pragma unroll
            for (int ks = 0; ks < 4; ++ks)
                aq[mt][ks] = *(const bf16x8*)(qb + (mt * 16 + l15) * 128 + ks * 32 + l4 * 8);
    }

    bf16x8 bones;   // col-0 ones -> P row sums via MFMA
    {
        __bf16 e = (l15 == 0) ? (__bf16)1.0f : (__bf16)0.0f;
#pragma unroll
        for (int i = 0; i < 8; ++i) bones[i] = e;
    }

    f32x4 o[2][8], ol[2];
#pragma unroll
    for (int mt = 0; mt < 2; ++mt) {
        ol[mt] = (f32x4){0.f, 0.f, 0.f, 0.f};
#pragma unroll
        for (int nt = 0; nt < 8; ++nt) o[mt][nt] = (f32x4){0.f, 0.f, 0.f, 0.f};
    }

    const u16* Kbase = Kb + (size_t)(b * 4 + kv) * TTOT * 128;
    const u16* Vbase = VtG + (size_t)(b * 4 + kv) * 128 * TTOT;
    const float* mrow = mask + (size_t)b * 64 * TTOT;
    u16* P = Psh[w];

    const int kp = tid >> 4, kd8 = (tid & 15) * 8;   // K rows kp, kp+32
    const int vr = tid >> 3, vc8 = (tid & 7) * 8;    // V rows vr, vr+64
    const int mq_ = tid >> 3, mk8 = (tid & 7) * 8;   // mask row, col block

    s16x8 rk0, rk1, rv0, rv1;
    float4 rm0, rm1;

    auto ld = [&](int t) {
        const int p = t * 64;
        rk0 = *(const s16x8*)(Kbase + (size_t)(p + kp) * 128 + kd8);
        rk1 = *(const s16x8*)(Kbase + (size_t)(p + kp + 32) * 128 + kd8);
        rv0 = *(const s16x8*)(Vbase + (size_t)vr * TTOT + p + vc8);
        rv1 = *(const s16x8*)(Vbase + (size_t)(vr + 64) * TTOT + p + vc8);
        const float* mp = mrow + (size_t)mq_ * TTOT + p + mk8;
        rm0 = *(const float4*)mp;
        rm1 = *(const float4*)(mp + 4);
        __builtin_amdgcn_sched_barrier(0);   // pin load issue here
    };
    auto st = [&](int buf) {
        *(s16x8*)(Ksh[buf] + kp * 136 + kd8) = rk0;
        *(s16x8*)(Ksh[buf] + (kp + 32) * 136 + kd8) = rk1;
        *(s16x8*)(Vsh[buf] + vr * 72 + vc8) = rv0;
        *(s16x8*)(Vsh[buf] + (vr + 64) * 72 + vc8) = rv1;
        float* md = Msh[buf] + mq_ * 68 + mk8;
        md[0] = fmaf(rm0.x, LOG2E, -MFIX); md[1] = fmaf(rm0.y, LOG2E, -MFIX);
        md[2] = fmaf(rm0.z, LOG2E, -MFIX); md[3] = fmaf(rm0.w, LOG2E, -MFIX);
        md[4] = fmaf(rm1.x, LOG2E, -MFIX); md[5] = fmaf(rm1.y, LOG2E, -MFIX);
        md[6] = fmaf(rm1.z, LOG2E, -MFIX); md[7] = fmaf(rm1.w, LOG2E, -MFIX);
    };

    // prologue
    ld(t0);
    st(0);
    __syncthreads();
    if (t0 + 1 < t1) ld(t0 + 1);

    int cur = 0;
    for (int t = t0; t < t1; ++t) {
        // ---- compute tile t from buf[cur] ----
        f32x4 sc[2][4];
#pragma unroll
        for (int mt = 0; mt < 2; ++mt)
#pragma unroll
            for (int nt = 0; nt < 4; ++nt) sc[mt][nt] = (f32x4){0.f, 0.f, 0.f, 0.f};
#pragma unroll
        for (int nt = 0; nt < 4; ++nt) {
#pragma unroll
            for (int ks = 0; ks < 4; ++ks) {
                bf16x8 bk = *(const bf16x8*)(Ksh[cur] + (nt * 16 + l15) * 136 + ks * 32 + l4 * 8);
                sc[0][nt] = mfma16(aq[0][ks], bk, sc[0][nt]);
                sc[1][nt] = mfma16(aq[1][ks], bk, sc[1][nt]);
            }
        }

        // fixed-max softmax: p = exp2(sc + msh), msh = mask*log2e - MFIX
#pragma unroll
        for (int mt = 0; mt < 2; ++mt) {
#pragma unroll
            for (int r = 0; r < 4; ++r) {
                const int q = qbase + mt * 16 + l4 * 4 + r;
                const float* mq = Msh[cur] + q * 68 + l15;
                sc[mt][0][r] = exp2f(sc[mt][0][r] + mq[0]);
                sc[mt][1][r] = exp2f(sc[mt][1][r] + mq[16]);
                sc[mt][2][r] = exp2f(sc[mt][2][r] + mq[32]);
                sc[mt][3][r] = exp2f(sc[mt][3][r] + mq[48]);
            }
        }

        // O += P V ; l += P 1
#pragma unroll
        for (int ks = 0; ks < 2; ++ks) {
#pragma unroll
            for (int mt = 0; mt < 2; ++mt)
#pragma unroll
                for (int r = 0; r < 4; ++r) {
                    P[(mt * 16 + l4 * 4 + r) * 40 + l15]      = f2bf(sc[mt][ks * 2 + 0][r]);
                    P[(mt * 16 + l4 * 4 + r) * 40 + 16 + l15] = f2bf(sc[mt][ks * 2 + 1][r]);
                }
            bf16x8 ap0 = *(const bf16x8*)(P + (l15) * 40 + l4 * 8);
            bf16x8 ap1 = *(const bf16x8*)(P + (16 + l15) * 40 + l4 * 8);
#pragma unroll
            for (int nt = 0; nt < 8; ++nt) {
                bf16x8 bv = *(const bf16x8*)(Vsh[cur] + (nt * 16 + l15) * 72 + ks * 32 + l4 * 8);
                o[0][nt] = mfma16(ap0, bv, o[0][nt]);
                o[1][nt] = mfma16(ap1, bv, o[1][nt]);
            }
            ol[0] = mfma16(ap0, bones, ol[0]);
            ol[1] = mfma16(ap1, bones, ol[1]);
        }

        // ---- stage tile t+1 into buf[cur^1]; prefetch t+2 ----
        if (t + 1 < t1) st(cur ^ 1);      // waits vmcnt for ld(t+1) regs here
        __syncthreads();                  // vmcnt already 0: no drain cost
        if (t + 2 < t1) ld(t + 2);        // in flight across next compute
        cur ^= 1;
    }

    // coalesced epilogue: Opart chunk per (b,h,s) = [qh][mt][nt][lane][r] u16
    {
        u16* ob = Opart + ((size_t)((b * 16 + h) * S + s)) * 8192;
#pragma unroll
        for (int mt = 0; mt < 2; ++mt)
#pragma unroll
            for (int nt = 0; nt < 8; ++nt) {
                u16x4 v;
#pragma unroll
                for (int r = 0; r < 4; ++r) v[r] = f2bf(o[mt][nt][r]);
                *(u16x4*)(ob + (((qh * 2 + mt) * 8 + nt) * 64 + lane) * 4) = v;
            }
        if (l15 == 0) {
#pragma unroll
            for (int mt = 0; mt < 2; ++mt)
#pragma unroll
                for (int r = 0; r < 4; ++r) {
                    const int q = qbase + mt * 16 + l4 * 4 + r;
                    lsum[((size_t)((b * 16 + h) * 64 + q)) * S + s] = ol[mt][r];
                }
        }
    }
}

// ---------------- merge splits -> attn (B,K,NH*HD) f32 --------------------
template <int S>
__global__ __launch_bounds__(256) void merge_kernel(
    const u16* __restrict__ Opart, const float* __restrict__ lsum, float* __restrict__ attnb)
{
    const int wid = blockIdx.x * 4 + (threadIdx.x >> 6);   // (b*16+h)*2 + qh
    const int lane = threadIdx.x & 63;
    const int l15 = lane & 15, l4 = lane >> 4;
    const int qh = wid & 1, bh = wid >> 1;
    const int h = bh & 15, b = bh >> 4;

    float L = 0.f;
    {
        const float* lr = lsum + ((size_t)bh * 64 + qh * 32 + (lane & 31)) * S;
#pragma unroll
        for (int s2 = 0; s2 < S; ++s2) L += lr[s2];
    }
    const float invL = 1.0f / L;

    float acc[2][8][4];
#pragma unroll
    for (int mt = 0; mt < 2; ++mt)
#pragma unroll
        for (int nt = 0; nt < 8; ++nt)
#pragma unroll
            for (int r = 0; r < 4; ++r) acc[mt][nt][r] = 0.f;

    for (int s2 = 0; s2 < S; ++s2) {
        const u16* ob = Opart + ((size_t)(bh * S + s2)) * 8192;
#pragma unroll
        for (int mt = 0; mt < 2; ++mt)
#pragma unroll
            for (int nt = 0; nt < 8; ++nt) {
                u16x4 v = *(const u16x4*)(ob + (((qh * 2 + mt) * 8 + nt) * 64 + lane) * 4);
#pragma unroll
                for (int r = 0; r < 4; ++r) acc[mt][nt][r] += bf2f(v[r]);
            }
    }

#pragma unroll
    for (int mt = 0; mt < 2; ++mt)
#pragma unroll
        for (int r = 0; r < 4; ++r) {
            const float wl = __shfl(invL, mt * 16 + l4 * 4 + r);
            const int q = qh * 32 + mt * 16 + l4 * 4 + r;
            float* dst = attnb + (size_t)(b * 64 + q) * 2048 + h * 128;
#pragma unroll
            for (int nt = 0; nt < 8; ++nt)
                dst[nt * 16 + l15] = acc[mt][nt][r] * wl;
        }
}

// ---------------- launch ----------------
extern "C" void kernel_launch(void* const* d_in, const int* in_sizes, int n_in,
                              void* d_out, int out_size, void* d_ws, size_t ws_size,
                              hipStream_t stream)
{
    (void)in_sizes; (void)n_in; (void)out_size; (void)ws_size;
    const float* hs   = (const float*)d_in[0];
    const float* ctxk = (const float*)d_in[1];
    const float* ctxv = (const float*)d_in[2];
    const float* mask = (const float*)d_in[3];
    const float* cosT = (const float*)d_in[4];
    const float* sinT = (const float*)d_in[5];
    const float* wq   = (const float*)d_in[6];
    const float* wk   = (const float*)d_in[7];
    const float* wv   = (const float*)d_in[8];
    const float* wo   = (const float*)d_in[9];
    const float* qnw  = (const float*)d_in[10];
    const float* knw  = (const float*)d_in[11];

    const int S = 8;

    char* ws = (char*)d_ws;
    size_t off = 0;
    auto carve = [&](size_t bytes) -> void* {
        void* p = ws + off;
        off += (bytes + 255) & ~(size_t)255;
        return p;
    };
    float* qkv   = (float*)carve((size_t)512 * 3072 * 4);               // 6.3 MB
    u16*   Qb    = (u16*)carve((size_t)BB * NH * 64 * 128 * 2);         // 2.1 MB
    u16*   Kb    = (u16*)carve((size_t)BB * NKV * TTOT * 128 * 2);      // 34.1 MB
    u16*   VtG   = (u16*)carve((size_t)BB * NKV * TTOT * 128 * 2);      // 34.1 MB
    u16*   Opart = (u16*)carve((size_t)BB * NH * S * 8192 * 2);         // 16.8 MB
    float* lsumb = (float*)carve((size_t)BB * NH * 64 * S * 4);         // 0.26 MB
    float* attnb = (float*)carve((size_t)512 * 2048 * 4);               // 4.2 MB
    // time-multiplexed aliases (stream-ordered, no overlap in liveness):
    //  - qkvp (4x512x3072 f32 = 25.2 MB) lives in VtG's slot; dead before
    //    build_vt runs.
    //  - outp (4x512x2048 f32 = 16.8 MB) lives in Kb's slot; Kb dead after
    //    attn_partial.
    float* qkvp = (float*)VtG;
    float* outp = (float*)Kb;

    // 1) QKV projection, split-K x4 -> partials -> reduce
    gemm_qkv_sk<4><<<dim3(8, 48, 4), 256, 0, stream>>>(hs, wq, wk, wv, qkvp);
    reduce4<<<1536, 256, 0, stream>>>(qkvp, qkv, (size_t)512 * 3072);
    // 2) norm + rope + cast (+ V transposed)
    finalize_q <<<1024,  256, 0, stream>>>(qkv, qnw, cosT, sinT, Qb);
    build_k    <<<16384, 256, 0, stream>>>(ctxk, knw, cosT, sinT, Kb);
    build_vt   <<<dim3(64, NKV, BB), 256, 0, stream>>>(ctxv, VtG);
    build_noise<<<256,   256, 0, stream>>>(qkv, knw, cosT, sinT, Kb, VtG);
    // 3) flash attention + merge
    attn_partial<8><<<dim3(8, NKV, BB), 512, 0, stream>>>(Qb, Kb, VtG, mask, Opart, lsumb);
    merge_kernel<8><<<64, 256, 0, stream>>>(Opart, lsumb, attnb);
    // 4) output projection, split-K x4 -> partials -> reduce into d_out
    gemm64_sk<4><<<dim3(8, 32, 4), 256, 0, stream>>>(attnb, wo, outp, 512, 2048, 2048);
    reduce4<<<1024, 256, 0, stream>>>(outp, (float*)d_out, (size_t)512 * 2048);
}

// Round 9
// 164.519 us; speedup vs baseline: 1.1019x; 1.1019x over previous
//
#include <hip/hip_runtime.h>

// ---------------- problem constants ----------------
#define BB   8
#define KQ   64
#define HDIM 2048
#define NH   16
#define NKV  4
#define HD   128
#define CTX  4096
#define TTOT 4160      // CTX + KQ
#define NTILES 65      // TTOT / 64
#define LOG2E 1.4426950408889634f
#define SCALE 0.08838834764831845f  // 1/sqrt(128)
#define QSCALE (SCALE * LOG2E)      // folded into Q; exp2-domain softmax
// |q.k| <= 128 after RMS-norm => |sc| <= 128*QSCALE = 16.33. Fixed softmax max.
#define MFIX 16.34f

typedef unsigned short u16;
typedef unsigned int   u32;
typedef __attribute__((ext_vector_type(8))) short  s16x8;   // bf16 storage
typedef __attribute__((ext_vector_type(4))) unsigned short u16x4;
typedef __attribute__((ext_vector_type(4))) float  f32x4;
typedef __bf16 bf16x8 __attribute__((ext_vector_type(8)));  // MFMA operand

__device__ __forceinline__ u16 f2bf(float f) {              // HW RNE cvt
    union { __bf16 h; u16 u; } v; v.h = (__bf16)f; return v.u;
}
__device__ __forceinline__ float bf2f(u16 u) {
    union { float f; u32 u; } v; v.u = ((u32)u) << 16;
    return v.f;
}
__device__ __forceinline__ u32 pack2(float a, float b) {
    return (u32)f2bf(a) | ((u32)f2bf(b) << 16);
}
__device__ __forceinline__ f32x4 mfma16(bf16x8 a, bf16x8 b, f32x4 c) {
    return __builtin_amdgcn_mfma_f32_16x16x32_bf16(a, b, c, 0, 0, 0);
}

// ---------------- f32 -> bf16 streaming cast (8 elems/thread) -------------
__global__ __launch_bounds__(256) void cast_bf16(
    const float* __restrict__ src, u16* __restrict__ dst, const int n8)
{
    const int i = blockIdx.x * 256 + threadIdx.x;
    if (i >= n8) return;
    float4 a = *(const float4*)(src + (size_t)i * 8);
    float4 b = *(const float4*)(src + (size_t)i * 8 + 4);
    s16x8 v;
    v[0]=(short)f2bf(a.x); v[1]=(short)f2bf(a.y); v[2]=(short)f2bf(a.z); v[3]=(short)f2bf(a.w);
    v[4]=(short)f2bf(b.x); v[5]=(short)f2bf(b.y); v[6]=(short)f2bf(b.z); v[7]=(short)f2bf(b.w);
    *(s16x8*)(dst + (size_t)i * 8) = v;
}

// ---------------- 64x64-tile GEMM core, bf16 inputs (padded LDS) ----------
// Round-8 lesson: the f32 version was FETCH-bound (100 MB at ~3 TB/s = 44us,
// Mfma/VALU ~5%, occupancy-insensitive). bf16 inputs halve bytes; the XCD
// swizzle in the callers makes weight-panel re-reads L2-local.
__device__ __forceinline__ void gemm64_body(
    const u16* __restrict__ Ab, const u16* __restrict__ Bb,
    float* __restrict__ Cb, const int ldc, const int ldk, const int Klen,
    u16* Ash, u16* Bsh)
{
    const int tid = threadIdx.x, lane = tid & 63;
    const int w = tid >> 6, wm = w >> 1, wn = w & 1;
    const int l15 = lane & 15, l4 = lane >> 4;
    const int srow = tid >> 2, scol = (tid & 3) * 16;

    f32x4 acc[2][2];
#pragma unroll
    for (int i = 0; i < 2; ++i)
#pragma unroll
        for (int j = 0; j < 2; ++j) acc[i][j] = (f32x4){0.f, 0.f, 0.f, 0.f};

    const u16* ap = Ab + (size_t)srow * ldk + scol;
    const u16* bp = Bb + (size_t)srow * ldk + scol;
    s16x8 ra0 = *(const s16x8*)ap, ra1 = *(const s16x8*)(ap + 8);
    s16x8 rb0 = *(const s16x8*)bp, rb1 = *(const s16x8*)(bp + 8);
    __builtin_amdgcn_sched_barrier(0);

    for (int k0 = 0; k0 < Klen; k0 += 64) {
        __syncthreads();
        *(s16x8*)(Ash + srow * 72 + scol)     = ra0;
        *(s16x8*)(Ash + srow * 72 + scol + 8) = ra1;
        *(s16x8*)(Bsh + srow * 72 + scol)     = rb0;
        *(s16x8*)(Bsh + srow * 72 + scol + 8) = rb1;
        __syncthreads();
        if (k0 + 64 < Klen) {   // prefetch next K-slab; live across MFMA phase
            const u16* ap2 = ap + k0 + 64;
            const u16* bp2 = bp + k0 + 64;
            ra0 = *(const s16x8*)ap2; ra1 = *(const s16x8*)(ap2 + 8);
            rb0 = *(const s16x8*)bp2; rb1 = *(const s16x8*)(bp2 + 8);
            __builtin_amdgcn_sched_barrier(0);
        }
#pragma unroll
        for (int ks = 0; ks < 2; ++ks) {
            bf16x8 am[2], bb[2];
#pragma unroll
            for (int i = 0; i < 2; ++i) {
                am[i] = *(const bf16x8*)(Ash + (wm * 32 + i * 16 + l15) * 72 + ks * 32 + l4 * 8);
                bb[i] = *(const bf16x8*)(Bsh + (wn * 32 + i * 16 + l15) * 72 + ks * 32 + l4 * 8);
            }
#pragma unroll
            for (int i = 0; i < 2; ++i)
#pragma unroll
                for (int j = 0; j < 2; ++j)
                    acc[i][j] = mfma16(am[i], bb[j], acc[i][j]);
        }
    }

    float* Cw = Cb + (size_t)(wm * 32) * ldc + wn * 32;
#pragma unroll
    for (int i = 0; i < 2; ++i)
#pragma unroll
        for (int j = 0; j < 2; ++j)
#pragma unroll
            for (int r = 0; r < 4; ++r)
                Cw[(size_t)(i * 16 + l4 * 4 + r) * ldc + j * 16 + l15] = acc[i][j][r];
}

// QKV projection, split-K x4, XCD-chunked swizzle. 1D grid 1536.
// Work linearized y-major: wid = x + 8*kc + 32*y. Each XCD (bid&7) owns a
// contiguous 192-wid chunk = 6 weight panels (1.5 MB bf16) + A (2 MB) < L2.
__global__ __launch_bounds__(256) void gemm_qkv_sk(
    const u16* __restrict__ hsb, const u16* __restrict__ wqkvb,
    float* __restrict__ qkvp)
{
    __shared__ __align__(16) u16 Ash[64 * 72];
    __shared__ __align__(16) u16 Bsh[64 * 72];
    const int wid = (blockIdx.x & 7) * 192 + (blockIdx.x >> 3);
    const int y = wid >> 5, rem = wid & 31, kc = rem >> 3, x = rem & 7;
    const int koff = kc * 512;
    const u16* Ab = hsb + (size_t)x * 64 * HDIM + koff;
    const u16* Bb = wqkvb + (size_t)y * 64 * HDIM + koff;
    float* Cb = qkvp + (size_t)kc * 512 * 3072 + (size_t)x * 64 * 3072 + y * 64;
    gemm64_body(Ab, Bb, Cb, 3072, HDIM, 512, Ash, Bsh);
}

// Output projection, split-K x4, XCD-chunked swizzle. 1D grid 1024.
__global__ __launch_bounds__(256) void gemm_out_sk(
    const u16* __restrict__ attnb, const u16* __restrict__ wob,
    float* __restrict__ outp)
{
    __shared__ __align__(16) u16 Ash[64 * 72];
    __shared__ __align__(16) u16 Bsh[64 * 72];
    const int wid = (blockIdx.x & 7) * 128 + (blockIdx.x >> 3);
    const int y = wid >> 5, rem = wid & 31, kc = rem >> 3, x = rem & 7;
    const int koff = kc * 512;
    const u16* Ab = attnb + (size_t)x * 64 * HDIM + koff;
    const u16* Bb = wob + (size_t)y * 64 * HDIM + koff;
    float* Cb = outp + (size_t)kc * 512 * 2048 + (size_t)x * 64 * 2048 + y * 64;
    gemm64_body(Ab, Bb, Cb, 2048, HDIM, 512, Ash, Bsh);
}

// sum 4 partial chunks -> out (float4 per thread), deterministic.
__global__ __launch_bounds__(256) void reduce4(
    const float* __restrict__ p, float* __restrict__ out, const size_t chunk)
{
    const size_t i = ((size_t)blockIdx.x * 256 + threadIdx.x) * 4;
    float4 a = *(const float4*)(p + i);
    float4 b = *(const float4*)(p + i + chunk);
    float4 c = *(const float4*)(p + i + 2 * chunk);
    float4 d = *(const float4*)(p + i + 3 * chunk);
    float4 r;
    r.x = (a.x + b.x) + (c.x + d.x);
    r.y = (a.y + b.y) + (c.y + d.y);
    r.z = (a.z + b.z) + (c.z + d.z);
    r.w = (a.w + b.w) + (c.w + d.w);
    *(float4*)(out + i) = r;
}

// ---------------- shared RMSNorm+RoPE helper (half-wave, float2-paired) ---
__device__ __forceinline__ void norm_rope_row(
    const float* __restrict__ src, const float* __restrict__ wgt,
    const float* __restrict__ cosT, const float* __restrict__ sinT,
    int pos, int j, float outScale, u16* __restrict__ dst)
{
    float2 xa = *(const float2*)(src + 2 * j);
    float2 xb = *(const float2*)(src + 2 * j + 64);
    float ss = xa.x * xa.x + xa.y * xa.y + xb.x * xb.x + xb.y * xb.y;
#pragma unroll
    for (int m = 1; m < 32; m <<= 1) ss += __shfl_xor(ss, m);
    const float rr = rsqrtf(ss * (1.0f / 128.0f) + 1e-6f);
    float2 wa = *(const float2*)(wgt + 2 * j);
    float2 wb = *(const float2*)(wgt + 2 * j + 64);
    const float* cp = cosT + (size_t)pos * 128;
    const float* sp = sinT + (size_t)pos * 128;
    float2 ca = *(const float2*)(cp + 2 * j), cb = *(const float2*)(cp + 2 * j + 64);
    float2 sa = *(const float2*)(sp + 2 * j), sb = *(const float2*)(sp + 2 * j + 64);
    const float nax = xa.x * rr * wa.x, nay = xa.y * rr * wa.y;
    const float nbx = xb.x * rr * wb.x, nby = xb.y * rr * wb.y;
    const float lox = (nax * ca.x - nbx * sa.x) * outScale;
    const float loy = (nay * ca.y - nby * sa.y) * outScale;
    const float hix = (nbx * cb.x + nax * sb.x) * outScale;
    const float hiy = (nby * cb.y + nay * sb.y) * outScale;
    ((u32*)dst)[j]      = pack2(lox, loy);
    ((u32*)dst)[j + 32] = pack2(hix, hiy);
}

__global__ __launch_bounds__(256) void finalize_q(
    const float* __restrict__ qkv, const float* __restrict__ qw,
    const float* __restrict__ cosT, const float* __restrict__ sinT, u16* __restrict__ Qb)
{
    const int unit = blockIdx.x * 8 + (threadIdx.x >> 5);   // bq*16 + h
    const int j = threadIdx.x & 31;
    const int bq = unit >> 4, h = unit & 15;
    const int b = bq >> 6, q = bq & 63;
    norm_rope_row(qkv + (size_t)bq * 3072 + h * 128, qw, cosT, sinT,
                  CTX + q, j, QSCALE,
                  Qb + ((size_t)((b * 16 + h) * 64 + q)) * 128);
}

__global__ __launch_bounds__(256) void build_k(
    const float* __restrict__ ctxk, const float* __restrict__ kw,
    const float* __restrict__ cosT, const float* __restrict__ sinT, u16* __restrict__ Kb)
{
    const int unit = blockIdx.x * 8 + (threadIdx.x >> 5);   // (b*4096+pos)*4 + kv
    const int j = threadIdx.x & 31;
    const int kv = unit & 3, rid = unit >> 2;
    const int b = rid >> 12, pos = rid & 4095;
    norm_rope_row(ctxk + ((size_t)rid * 4 + kv) * 128, kw, cosT, sinT,
                  pos, j, 1.0f,
                  Kb + ((size_t)(b * 4 + kv) * TTOT + pos) * 128);
}

__global__ __launch_bounds__(256) void build_vt(
    const float* __restrict__ ctxv, u16* __restrict__ VtG)
{
    const int pt = blockIdx.x, kv = blockIdx.y, b = blockIdx.z;
    const int t = threadIdx.x;
    const int d = t & 127, half = t >> 7;
    const int p0 = pt * 64 + half * 32;

    u16* dst = VtG + ((size_t)(b * 4 + kv) * 128 + d) * TTOT + p0;
    const float* src = ctxv + ((size_t)(b * 4096 + p0) * 4 + kv) * 128 + d;
#pragma unroll
    for (int j8 = 0; j8 < 4; ++j8) {
        s16x8 v;
#pragma unroll
        for (int je = 0; je < 8; ++je)
            v[je] = (short)f2bf(src[(size_t)(j8 * 8 + je) * 512]);
        *(s16x8*)(dst + j8 * 8) = v;
    }
}

__global__ __launch_bounds__(256) void build_noise(
    const float* __restrict__ qkv, const float* __restrict__ kw,
    const float* __restrict__ cosT, const float* __restrict__ sinT,
    u16* __restrict__ Kb, u16* __restrict__ VtG)
{
    const int unit = blockIdx.x * 8 + (threadIdx.x >> 5);   // bq*4 + kv
    const int j = threadIdx.x & 31;
    const int kv = unit & 3, bq = unit >> 2;
    const int b = bq >> 6, q = bq & 63;
    const int pos = CTX + q;

    norm_rope_row(qkv + (size_t)bq * 3072 + 2048 + kv * 128, kw, cosT, sinT,
                  pos, j, 1.0f,
                  Kb + ((size_t)(b * 4 + kv) * TTOT + pos) * 128);

    const float* vsrc = qkv + (size_t)bq * 3072 + 2560 + kv * 128;
    float2 va = *(const float2*)(vsrc + 2 * j);
    float2 vb = *(const float2*)(vsrc + 2 * j + 64);
    u16* vt = VtG + (size_t)(b * 4 + kv) * 128 * TTOT;
    vt[(size_t)(2 * j) * TTOT + pos]      = f2bf(va.x);
    vt[(size_t)(2 * j + 1) * TTOT + pos]  = f2bf(va.y);
    vt[(size_t)(2 * j + 64) * TTOT + pos] = f2bf(vb.x);
    vt[(size_t)(2 * j + 65) * TTOT + pos] = f2bf(vb.y);
}

// ---------------- flash attention partial: pipelined double-buffer --------
// (round-6 proven: 1 block/CU, LDS 124 KB, loads never in flight at barrier)
// + T5 setprio around MFMA clusters (phase-split schedule -> applicable).
template <int S>
__global__ __launch_bounds__(512, 2) void attn_partial(
    const u16* __restrict__ Qb, const u16* __restrict__ Kb, const u16* __restrict__ VtG,
    const float* __restrict__ mask, u16* __restrict__ Opart, float* __restrict__ lsum)
{
    __shared__ __align__(16) u16   Ksh[2][64 * 136];   // K [pos][d], padded
    __shared__ __align__(16) u16   Vsh[2][128 * 72];   // V^T [d][pos], padded
    __shared__ __align__(16) float Msh[2][64 * 68];    // mask*log2e - MFIX
    __shared__ __align__(16) u16   Psh[8][32 * 40];    // per-wave P chunk

    const int s = blockIdx.x, kv = blockIdx.y, b = blockIdx.z;
    const int tid = threadIdx.x, lane = tid & 63, w = tid >> 6;
    const int h = kv * 4 + (w >> 1);
    const int qh = w & 1, qbase = qh * 32;
    const int l15 = lane & 15, l4 = lane >> 4;
    const int t0 = (NTILES * s) / S, t1 = (NTILES * (s + 1)) / S;

    bf16x8 aq[2][4];
    {
        const u16* qb = Qb + ((size_t)((b * 16 + h) * 64 + qbase)) * 128;
#pragma unroll
        for (int mt = 0; mt < 2; ++mt)
#pragma unroll
            for (int ks = 0; ks < 4; ++ks)
                aq[mt][ks] = *(const bf16x8*)(qb + (mt * 16 + l15) * 128 + ks * 32 + l4 * 8);
    }

    bf16x8 bones;   // col-0 ones -> P row sums via MFMA
    {
        __bf16 e = (l15 == 0) ? (__bf16)1.0f : (__bf16)0.0f;
#pragma unroll
        for (int i = 0; i < 8; ++i) bones[i] = e;
    }

    f32x4 o[2][8], ol[2];
#pragma unroll
    for (int mt = 0; mt < 2; ++mt) {
        ol[mt] = (f32x4){0.f, 0.f, 0.f, 0.f};
#pragma unroll
        for (int nt = 0; nt < 8; ++nt) o[mt][nt] = (f32x4){0.f, 0.f, 0.f, 0.f};
    }

    const u16* Kbase = Kb + (size_t)(b * 4 + kv) * TTOT * 128;
    const u16* Vbase = VtG + (size_t)(b * 4 + kv) * 128 * TTOT;
    const float* mrow = mask + (size_t)b * 64 * TTOT;
    u16* P = Psh[w];

    const int kp = tid >> 4, kd8 = (tid & 15) * 8;   // K rows kp, kp+32
    const int vr = tid >> 3, vc8 = (tid & 7) * 8;    // V rows vr, vr+64
    const int mq_ = tid >> 3, mk8 = (tid & 7) * 8;   // mask row, col block

    s16x8 rk0, rk1, rv0, rv1;
    float4 rm0, rm1;

    auto ld = [&](int t) {
        const int p = t * 64;
        rk0 = *(const s16x8*)(Kbase + (size_t)(p + kp) * 128 + kd8);
        rk1 = *(const s16x8*)(Kbase + (size_t)(p + kp + 32) * 128 + kd8);
        rv0 = *(const s16x8*)(Vbase + (size_t)vr * TTOT + p + vc8);
        rv1 = *(const s16x8*)(Vbase + (size_t)(vr + 64) * TTOT + p + vc8);
        const float* mp = mrow + (size_t)mq_ * TTOT + p + mk8;
        rm0 = *(const float4*)mp;
        rm1 = *(const float4*)(mp + 4);
        __builtin_amdgcn_sched_barrier(0);   // pin load issue here
    };
    auto st = [&](int buf) {
        *(s16x8*)(Ksh[buf] + kp * 136 + kd8) = rk0;
        *(s16x8*)(Ksh[buf] + (kp + 32) * 136 + kd8) = rk1;
        *(s16x8*)(Vsh[buf] + vr * 72 + vc8) = rv0;
        *(s16x8*)(Vsh[buf] + (vr + 64) * 72 + vc8) = rv1;
        float* md = Msh[buf] + mq_ * 68 + mk8;
        md[0] = fmaf(rm0.x, LOG2E, -MFIX); md[1] = fmaf(rm0.y, LOG2E, -MFIX);
        md[2] = fmaf(rm0.z, LOG2E, -MFIX); md[3] = fmaf(rm0.w, LOG2E, -MFIX);
        md[4] = fmaf(rm1.x, LOG2E, -MFIX); md[5] = fmaf(rm1.y, LOG2E, -MFIX);
        md[6] = fmaf(rm1.z, LOG2E, -MFIX); md[7] = fmaf(rm1.w, LOG2E, -MFIX);
    };

    // prologue
    ld(t0);
    st(0);
    __syncthreads();
    if (t0 + 1 < t1) ld(t0 + 1);

    int cur = 0;
    for (int t = t0; t < t1; ++t) {
        // ---- compute tile t from buf[cur] ----
        f32x4 sc[2][4];
#pragma unroll
        for (int mt = 0; mt < 2; ++mt)
#pragma unroll
            for (int nt = 0; nt < 4; ++nt) sc[mt][nt] = (f32x4){0.f, 0.f, 0.f, 0.f};
        __builtin_amdgcn_s_setprio(1);
#pragma unroll
        for (int nt = 0; nt < 4; ++nt) {
#pragma unroll
            for (int ks = 0; ks < 4; ++ks) {
                bf16x8 bk = *(const bf16x8*)(Ksh[cur] + (nt * 16 + l15) * 136 + ks * 32 + l4 * 8);
                sc[0][nt] = mfma16(aq[0][ks], bk, sc[0][nt]);
                sc[1][nt] = mfma16(aq[1][ks], bk, sc[1][nt]);
            }
        }
        __builtin_amdgcn_s_setprio(0);

        // fixed-max softmax: p = exp2(sc + msh), msh = mask*log2e - MFIX
#pragma unroll
        for (int mt = 0; mt < 2; ++mt) {
#pragma unroll
            for (int r = 0; r < 4; ++r) {
                const int q = qbase + mt * 16 + l4 * 4 + r;
                const float* mq = Msh[cur] + q * 68 + l15;
                sc[mt][0][r] = exp2f(sc[mt][0][r] + mq[0]);
                sc[mt][1][r] = exp2f(sc[mt][1][r] + mq[16]);
                sc[mt][2][r] = exp2f(sc[mt][2][r] + mq[32]);
                sc[mt][3][r] = exp2f(sc[mt][3][r] + mq[48]);
            }
        }

        // O += P V ; l += P 1
#pragma unroll
        for (int ks = 0; ks < 2; ++ks) {
#pragma unroll
            for (int mt = 0; mt < 2; ++mt)
#pragma unroll
                for (int r = 0; r < 4; ++r) {
                    P[(mt * 16 + l4 * 4 + r) * 40 + l15]      = f2bf(sc[mt][ks * 2 + 0][r]);
                    P[(mt * 16 + l4 * 4 + r) * 40 + 16 + l15] = f2bf(sc[mt][ks * 2 + 1][r]);
                }
            bf16x8 ap0 = *(const bf16x8*)(P + (l15) * 40 + l4 * 8);
            bf16x8 ap1 = *(const bf16x8*)(P + (16 + l15) * 40 + l4 * 8);
            __builtin_amdgcn_s_setprio(1);
#pragma unroll
            for (int nt = 0; nt < 8; ++nt) {
                bf16x8 bv = *(const bf16x8*)(Vsh[cur] + (nt * 16 + l15) * 72 + ks * 32 + l4 * 8);
                o[0][nt] = mfma16(ap0, bv, o[0][nt]);
                o[1][nt] = mfma16(ap1, bv, o[1][nt]);
            }
            ol[0] = mfma16(ap0, bones, ol[0]);
            ol[1] = mfma16(ap1, bones, ol[1]);
            __builtin_amdgcn_s_setprio(0);
        }

        // ---- stage tile t+1 into buf[cur^1]; prefetch t+2 ----
        if (t + 1 < t1) st(cur ^ 1);      // waits vmcnt for ld(t+1) regs here
        __syncthreads();                  // vmcnt already 0: no drain cost
        if (t + 2 < t1) ld(t + 2);        // in flight across next compute
        cur ^= 1;
    }

    // coalesced epilogue: Opart chunk per (b,h,s) = [qh][mt][nt][lane][r] u16
    {
        u16* ob = Opart + ((size_t)((b * 16 + h) * S + s)) * 8192;
#pragma unroll
        for (int mt = 0; mt < 2; ++mt)
#pragma unroll
            for (int nt = 0; nt < 8; ++nt) {
                u16x4 v;
#pragma unroll
                for (int r = 0; r < 4; ++r) v[r] = f2bf(o[mt][nt][r]);
                *(u16x4*)(ob + (((qh * 2 + mt) * 8 + nt) * 64 + lane) * 4) = v;
            }
        if (l15 == 0) {
#pragma unroll
            for (int mt = 0; mt < 2; ++mt)
#pragma unroll
                for (int r = 0; r < 4; ++r) {
                    const int q = qbase + mt * 16 + l4 * 4 + r;
                    lsum[((size_t)((b * 16 + h) * 64 + q)) * S + s] = ol[mt][r];
                }
        }
    }
}

// ---------------- merge splits -> attn (B,K,NH*HD) bf16 -------------------
template <int S>
__global__ __launch_bounds__(256) void merge_kernel(
    const u16* __restrict__ Opart, const float* __restrict__ lsum, u16* __restrict__ attnb)
{
    const int wid = blockIdx.x * 4 + (threadIdx.x >> 6);   // (b*16+h)*2 + qh
    const int lane = threadIdx.x & 63;
    const int l15 = lane & 15, l4 = lane >> 4;
    const int qh = wid & 1, bh = wid >> 1;
    const int h = bh & 15, b = bh >> 4;

    float L = 0.f;
    {
        const float* lr = lsum + ((size_t)bh * 64 + qh * 32 + (lane & 31)) * S;
#pragma unroll
        for (int s2 = 0; s2 < S; ++s2) L += lr[s2];
    }
    const float invL = 1.0f / L;

    float acc[2][8][4];
#pragma unroll
    for (int mt = 0; mt < 2; ++mt)
#pragma unroll
        for (int nt = 0; nt < 8; ++nt)
#pragma unroll
            for (int r = 0; r < 4; ++r) acc[mt][nt][r] = 0.f;

    for (int s2 = 0; s2 < S; ++s2) {
        const u16* ob = Opart + ((size_t)(bh * S + s2)) * 8192;
#pragma unroll
        for (int mt = 0; mt < 2; ++mt)
#pragma unroll
            for (int nt = 0; nt < 8; ++nt) {
                u16x4 v = *(const u16x4*)(ob + (((qh * 2 + mt) * 8 + nt) * 64 + lane) * 4);
#pragma unroll
                for (int r = 0; r < 4; ++r) acc[mt][nt][r] += bf2f(v[r]);
            }
    }

#pragma unroll
    for (int mt = 0; mt < 2; ++mt)
#pragma unroll
        for (int r = 0; r < 4; ++r) {
            const float wl = __shfl(invL, mt * 16 + l4 * 4 + r);
            const int q = qh * 32 + mt * 16 + l4 * 4 + r;
            u16* dst = attnb + (size_t)(b * 64 + q) * 2048 + h * 128;
#pragma unroll
            for (int nt = 0; nt < 8; ++nt)
                dst[nt * 16 + l15] = f2bf(acc[mt][nt][r] * wl);
        }
}

// ---------------- launch ----------------
extern "C" void kernel_launch(void* const* d_in, const int* in_sizes, int n_in,
                              void* d_out, int out_size, void* d_ws, size_t ws_size,
                              hipStream_t stream)
{
    (void)in_sizes; (void)n_in; (void)out_size; (void)ws_size;
    const float* hs   = (const float*)d_in[0];
    const float* ctxk = (const float*)d_in[1];
    const float* ctxv = (const float*)d_in[2];
    const float* mask = (const float*)d_in[3];
    const float* cosT = (const float*)d_in[4];
    const float* sinT = (const float*)d_in[5];
    const float* wq   = (const float*)d_in[6];
    const float* wk   = (const float*)d_in[7];
    const float* wv   = (const float*)d_in[8];
    const float* wo   = (const float*)d_in[9];
    const float* qnw  = (const float*)d_in[10];
    const float* knw  = (const float*)d_in[11];

    const int S = 8;

    char* ws = (char*)d_ws;
    size_t off = 0;
    auto carve = [&](size_t bytes) -> void* {
        void* p = ws + off;
        off += (bytes + 255) & ~(size_t)255;
        return p;
    };
    float* qkv   = (float*)carve((size_t)512 * 3072 * 4);               // 6.3 MB
    u16*   Qb    = (u16*)carve((size_t)BB * NH * 64 * 128 * 2);         // 2.1 MB
    u16*   Kb    = (u16*)carve((size_t)BB * NKV * TTOT * 128 * 2);      // 34.1 MB
    u16*   VtG   = (u16*)carve((size_t)BB * NKV * TTOT * 128 * 2);      // 34.1 MB
    u16*   Opart = (u16*)carve((size_t)BB * NH * S * 8192 * 2);         // 16.8 MB
    float* lsumb = (float*)carve((size_t)BB * NH * 64 * S * 4);         // 0.26 MB
    u16*   attnb = (u16*)carve((size_t)512 * 2048 * 2);                 // 2.1 MB
    u16*   wob   = (u16*)carve((size_t)2048 * 2048 * 2);                // 8.4 MB
    // ~104 MB. Time-multiplexed aliases (stream-ordered liveness):
    u16*   wqkvb = (u16*)Kb;     // bf16 weights, dead before build_k
    float* qkvp  = (float*)VtG;  // qkv partials, dead before build_vt
    u16*   hsb   = (u16*)Opart;  // bf16 hs, dead before attn_partial
    float* outp  = (float*)Kb;   // out partials, Kb dead after attn_partial

    // 0) pre-cast weights + activations to bf16 (halves all GEMM fetch)
    cast_bf16<<<2048, 256, 0, stream>>>(wq, wqkvb,                 524288);
    cast_bf16<<<512,  256, 0, stream>>>(wk, wqkvb + 2048 * HDIM,   131072);
    cast_bf16<<<512,  256, 0, stream>>>(wv, wqkvb + 2560 * HDIM,   131072);
    cast_bf16<<<2048, 256, 0, stream>>>(wo, wob,                   524288);
    cast_bf16<<<512,  256, 0, stream>>>(hs, hsb,                   131072);
    // 1) QKV projection (bf16, split-K x4, XCD swizzle) -> reduce
    gemm_qkv_sk<<<1536, 256, 0, stream>>>(hsb, wqkvb, qkvp);
    reduce4<<<1536, 256, 0, stream>>>(qkvp, qkv, (size_t)512 * 3072);
    // 2) norm + rope + cast (+ V transposed)
    finalize_q <<<1024,  256, 0, stream>>>(qkv, qnw, cosT, sinT, Qb);
    build_k    <<<16384, 256, 0, stream>>>(ctxk, knw, cosT, sinT, Kb);
    build_vt   <<<dim3(64, NKV, BB), 256, 0, stream>>>(ctxv, VtG);
    build_noise<<<256,   256, 0, stream>>>(qkv, knw, cosT, sinT, Kb, VtG);
    // 3) flash attention + merge (attnb in bf16 for the out-proj)
    attn_partial<8><<<dim3(8, NKV, BB), 512, 0, stream>>>(Qb, Kb, VtG, mask, Opart, lsumb);
    merge_kernel<8><<<64, 256, 0, stream>>>(Opart, lsumb, attnb);
    // 4) output projection (bf16, split-K x4, XCD swizzle) -> reduce
    gemm_out_sk<<<1024, 256, 0, stream>>>(attnb, wob, outp);
    reduce4<<<1024, 256, 0, stream>>>(outp, (float*)d_out, (size_t)512 * 2048);
}

// Round 10
// 145.566 us; speedup vs baseline: 1.2453x; 1.1302x over previous
//
#include <hip/hip_runtime.h>

// ---------------- problem constants ----------------
#define BB   8
#define KQ   64
#define HDIM 2048
#define NH   16
#define NKV  4
#define HD   128
#define CTX  4096
#define TTOT 4160      // CTX + KQ
#define NTILES 65      // TTOT / 64
#define LOG2E 1.4426950408889634f
#define SCALE 0.08838834764831845f  // 1/sqrt(128)
#define QSCALE (SCALE * LOG2E)      // folded into Q; exp2-domain softmax
// |q.k| <= 128 after RMS-norm => |sc| <= 128*QSCALE = 16.33. Fixed softmax max.
#define MFIX 16.34f

typedef unsigned short u16;
typedef unsigned int   u32;
typedef __attribute__((ext_vector_type(8))) short  s16x8;   // bf16 storage
typedef __attribute__((ext_vector_type(4))) unsigned short u16x4;
typedef __attribute__((ext_vector_type(4))) float  f32x4;
typedef __bf16 bf16x8 __attribute__((ext_vector_type(8)));  // MFMA operand

__device__ __forceinline__ u16 f2bf(float f) {              // HW RNE cvt
    union { __bf16 h; u16 u; } v; v.h = (__bf16)f; return v.u;
}
__device__ __forceinline__ float bf2f(u16 u) {
    union { float f; u32 u; } v; v.u = ((u32)u) << 16;
    return v.f;
}
__device__ __forceinline__ u32 pack2(float a, float b) {
    return (u32)f2bf(a) | ((u32)f2bf(b) << 16);
}
__device__ __forceinline__ f32x4 mfma16(bf16x8 a, bf16x8 b, f32x4 c) {
    return __builtin_amdgcn_mfma_f32_16x16x32_bf16(a, b, c, 0, 0, 0);
}

// ---------------- fused f32 -> bf16 cast of all 5 tensors -----------------
// groups of 8 elems. wq:0..524288, wk:..655360, wv:..786432, wo:..1310720,
// hs:..1441792. wq/wk/wv pack contiguously into wqkvb (3072x2048).
__global__ __launch_bounds__(256) void cast_all(
    const float* __restrict__ wq, const float* __restrict__ wk,
    const float* __restrict__ wv, const float* __restrict__ wo,
    const float* __restrict__ hs,
    u16* __restrict__ wqkvb, u16* __restrict__ wob, u16* __restrict__ hsb)
{
    const int i = blockIdx.x * 256 + threadIdx.x;
    const float* src; u16* dst;
    if (i < 524288)       { src = wq + (size_t)i * 8;             dst = wqkvb + (size_t)i * 8; }
    else if (i < 655360)  { src = wk + (size_t)(i - 524288) * 8;  dst = wqkvb + (size_t)i * 8; }
    else if (i < 786432)  { src = wv + (size_t)(i - 655360) * 8;  dst = wqkvb + (size_t)i * 8; }
    else if (i < 1310720) { src = wo + (size_t)(i - 786432) * 8;  dst = wob + (size_t)(i - 786432) * 8; }
    else                  { src = hs + (size_t)(i - 1310720) * 8; dst = hsb + (size_t)(i - 1310720) * 8; }
    float4 a = *(const float4*)src;
    float4 b = *(const float4*)(src + 4);
    s16x8 v;
    v[0]=(short)f2bf(a.x); v[1]=(short)f2bf(a.y); v[2]=(short)f2bf(a.z); v[3]=(short)f2bf(a.w);
    v[4]=(short)f2bf(b.x); v[5]=(short)f2bf(b.y); v[6]=(short)f2bf(b.z); v[7]=(short)f2bf(b.w);
    *(s16x8*)dst = v;
}

// ---------------- 64x64-tile GEMM core, bf16 inputs (padded LDS) ----------
__device__ __forceinline__ void gemm64_body(
    const u16* __restrict__ Ab, const u16* __restrict__ Bb,
    float* __restrict__ Cb, const int ldc, const int ldk, const int Klen,
    u16* Ash, u16* Bsh)
{
    const int tid = threadIdx.x, lane = tid & 63;
    const int w = tid >> 6, wm = w >> 1, wn = w & 1;
    const int l15 = lane & 15, l4 = lane >> 4;
    const int srow = tid >> 2, scol = (tid & 3) * 16;

    f32x4 acc[2][2];
#pragma unroll
    for (int i = 0; i < 2; ++i)
#pragma unroll
        for (int j = 0; j < 2; ++j) acc[i][j] = (f32x4){0.f, 0.f, 0.f, 0.f};

    const u16* ap = Ab + (size_t)srow * ldk + scol;
    const u16* bp = Bb + (size_t)srow * ldk + scol;
    s16x8 ra0 = *(const s16x8*)ap, ra1 = *(const s16x8*)(ap + 8);
    s16x8 rb0 = *(const s16x8*)bp, rb1 = *(const s16x8*)(bp + 8);
    __builtin_amdgcn_sched_barrier(0);

    for (int k0 = 0; k0 < Klen; k0 += 64) {
        __syncthreads();
        *(s16x8*)(Ash + srow * 72 + scol)     = ra0;
        *(s16x8*)(Ash + srow * 72 + scol + 8) = ra1;
        *(s16x8*)(Bsh + srow * 72 + scol)     = rb0;
        *(s16x8*)(Bsh + srow * 72 + scol + 8) = rb1;
        __syncthreads();
        if (k0 + 64 < Klen) {
            const u16* ap2 = ap + k0 + 64;
            const u16* bp2 = bp + k0 + 64;
            ra0 = *(const s16x8*)ap2; ra1 = *(const s16x8*)(ap2 + 8);
            rb0 = *(const s16x8*)bp2; rb1 = *(const s16x8*)(bp2 + 8);
            __builtin_amdgcn_sched_barrier(0);
        }
#pragma unroll
        for (int ks = 0; ks < 2; ++ks) {
            bf16x8 am[2], bb[2];
#pragma unroll
            for (int i = 0; i < 2; ++i) {
                am[i] = *(const bf16x8*)(Ash + (wm * 32 + i * 16 + l15) * 72 + ks * 32 + l4 * 8);
                bb[i] = *(const bf16x8*)(Bsh + (wn * 32 + i * 16 + l15) * 72 + ks * 32 + l4 * 8);
            }
#pragma unroll
            for (int i = 0; i < 2; ++i)
#pragma unroll
                for (int j = 0; j < 2; ++j)
                    acc[i][j] = mfma16(am[i], bb[j], acc[i][j]);
        }
    }

    float* Cw = Cb + (size_t)(wm * 32) * ldc + wn * 32;
#pragma unroll
    for (int i = 0; i < 2; ++i)
#pragma unroll
        for (int j = 0; j < 2; ++j)
#pragma unroll
            for (int r = 0; r < 4; ++r)
                Cw[(size_t)(i * 16 + l4 * 4 + r) * ldc + j * 16 + l15] = acc[i][j][r];
}

// QKV projection, split-K x4, XCD-chunked swizzle. 1D grid 1536.
__global__ __launch_bounds__(256) void gemm_qkv_sk(
    const u16* __restrict__ hsb, const u16* __restrict__ wqkvb,
    float* __restrict__ qkvp)
{
    __shared__ __align__(16) u16 Ash[64 * 72];
    __shared__ __align__(16) u16 Bsh[64 * 72];
    const int wid = (blockIdx.x & 7) * 192 + (blockIdx.x >> 3);
    const int y = wid >> 5, rem = wid & 31, kc = rem >> 3, x = rem & 7;
    const int koff = kc * 512;
    const u16* Ab = hsb + (size_t)x * 64 * HDIM + koff;
    const u16* Bb = wqkvb + (size_t)y * 64 * HDIM + koff;
    float* Cb = qkvp + (size_t)kc * 512 * 3072 + (size_t)x * 64 * 3072 + y * 64;
    gemm64_body(Ab, Bb, Cb, 3072, HDIM, 512, Ash, Bsh);
}

// Output projection, split-K x4, XCD-chunked swizzle. 1D grid 1024.
__global__ __launch_bounds__(256) void gemm_out_sk(
    const u16* __restrict__ attnb, const u16* __restrict__ wob,
    float* __restrict__ outp)
{
    __shared__ __align__(16) u16 Ash[64 * 72];
    __shared__ __align__(16) u16 Bsh[64 * 72];
    const int wid = (blockIdx.x & 7) * 128 + (blockIdx.x >> 3);
    const int y = wid >> 5, rem = wid & 31, kc = rem >> 3, x = rem & 7;
    const int koff = kc * 512;
    const u16* Ab = attnb + (size_t)x * 64 * HDIM + koff;
    const u16* Bb = wob + (size_t)y * 64 * HDIM + koff;
    float* Cb = outp + (size_t)kc * 512 * 2048 + (size_t)x * 64 * 2048 + y * 64;
    gemm64_body(Ab, Bb, Cb, 2048, HDIM, 512, Ash, Bsh);
}

// sum 4 partial chunks -> out (float4 per thread), deterministic.
__global__ __launch_bounds__(256) void reduce4(
    const float* __restrict__ p, float* __restrict__ out, const size_t chunk)
{
    const size_t i = ((size_t)blockIdx.x * 256 + threadIdx.x) * 4;
    float4 a = *(const float4*)(p + i);
    float4 b = *(const float4*)(p + i + chunk);
    float4 c = *(const float4*)(p + i + 2 * chunk);
    float4 d = *(const float4*)(p + i + 3 * chunk);
    float4 r;
    r.x = (a.x + b.x) + (c.x + d.x);
    r.y = (a.y + b.y) + (c.y + d.y);
    r.z = (a.z + b.z) + (c.z + d.z);
    r.w = (a.w + b.w) + (c.w + d.w);
    *(float4*)(out + i) = r;
}

// ---------------- RMSNorm+RoPE on in-register values (half-wave) ----------
__device__ __forceinline__ void norm_rope_vals(
    float2 xa, float2 xb, const float* __restrict__ wgt,
    const float* __restrict__ cosT, const float* __restrict__ sinT,
    int pos, int j, float outScale, u16* __restrict__ dst)
{
    float ss = xa.x * xa.x + xa.y * xa.y + xb.x * xb.x + xb.y * xb.y;
#pragma unroll
    for (int m = 1; m < 32; m <<= 1) ss += __shfl_xor(ss, m);
    const float rr = rsqrtf(ss * (1.0f / 128.0f) + 1e-6f);
    float2 wa = *(const float2*)(wgt + 2 * j);
    float2 wb = *(const float2*)(wgt + 2 * j + 64);
    const float* cp = cosT + (size_t)pos * 128;
    const float* sp = sinT + (size_t)pos * 128;
    float2 ca = *(const float2*)(cp + 2 * j), cb = *(const float2*)(cp + 2 * j + 64);
    float2 sa = *(const float2*)(sp + 2 * j), sb = *(const float2*)(sp + 2 * j + 64);
    const float nax = xa.x * rr * wa.x, nay = xa.y * rr * wa.y;
    const float nbx = xb.x * rr * wb.x, nby = xb.y * rr * wb.y;
    const float lox = (nax * ca.x - nbx * sa.x) * outScale;
    const float loy = (nay * ca.y - nby * sa.y) * outScale;
    const float hix = (nbx * cb.x + nax * sb.x) * outScale;
    const float hiy = (nby * cb.y + nay * sb.y) * outScale;
    ((u32*)dst)[j]      = pack2(lox, loy);
    ((u32*)dst)[j + 32] = pack2(hix, hiy);
}

// ---------------- fused split-K reduce + RMSNorm/RoPE/cast ----------------
// Replaces reduce4(qkv) + finalize_q + build_noise. Half-wave per (bq, slot),
// slot: 0..15 q heads -> Qb; 16..19 k-noise -> knb; 20..23 v-noise -> vnb.
// grid 1536 x 256 (12288 units).
__global__ __launch_bounds__(256) void finalize_qkv(
    const float* __restrict__ qkvp, const float* __restrict__ qw,
    const float* __restrict__ kw, const float* __restrict__ cosT,
    const float* __restrict__ sinT,
    u16* __restrict__ Qb, u16* __restrict__ knb, u16* __restrict__ vnb)
{
    const int unit = blockIdx.x * 8 + (threadIdx.x >> 5);
    const int j = threadIdx.x & 31;
    const int slot = unit % 24, bq = unit / 24;
    const int b = bq >> 6, q = bq & 63;
    const int col0 = (slot < 16) ? slot * 128
                   : (slot < 20) ? 2048 + (slot - 16) * 128
                                 : 2560 + (slot - 20) * 128;
    const float* base = qkvp + (size_t)bq * 3072 + col0;

    float2 xa = {0.f, 0.f}, xb = {0.f, 0.f};
#pragma unroll
    for (int kc = 0; kc < 4; ++kc) {
        const float* p = base + (size_t)kc * 512 * 3072;
        float2 a = *(const float2*)(p + 2 * j);
        float2 c = *(const float2*)(p + 2 * j + 64);
        xa.x += a.x; xa.y += a.y; xb.x += c.x; xb.y += c.y;
    }

    if (slot < 16) {
        norm_rope_vals(xa, xb, qw, cosT, sinT, CTX + q, j, QSCALE,
                       Qb + ((size_t)((b * 16 + slot) * 64 + q)) * 128);
    } else if (slot < 20) {
        norm_rope_vals(xa, xb, kw, cosT, sinT, CTX + q, j, 1.0f,
                       knb + ((size_t)((b * 4 + (slot - 16)) * 64 + q)) * 128);
    } else {
        u16* dst = vnb + ((size_t)((b * 4 + (slot - 20)) * 64 + q)) * 128;
        ((u32*)dst)[j]      = pack2(xa.x, xa.y);
        ((u32*)dst)[j + 32] = pack2(xb.x, xb.y);
    }
}

// ---------------- fused ctx build: K norm+rope, V^T, noise scatter --------
// blocks [0,16384): ctx K rows.  [16384,18432): ctx V^T tiles.
// [18432,18464): knb -> Kb noise rows (plain copy).
// [18464,18496): vnb -> VtG noise cols (64x128 transpose).
__global__ __launch_bounds__(256) void build_ctx(
    const float* __restrict__ ctxk, const float* __restrict__ kw,
    const float* __restrict__ cosT, const float* __restrict__ sinT,
    const float* __restrict__ ctxv, const u16* __restrict__ knb,
    const u16* __restrict__ vnb, u16* __restrict__ Kb, u16* __restrict__ VtG)
{
    const int bid = blockIdx.x;
    if (bid < 16384) {
        // ---- ctx K: half-wave per (b,pos,kv) ----
        const int unit = bid * 8 + (threadIdx.x >> 5);   // (b*4096+pos)*4 + kv
        const int j = threadIdx.x & 31;
        const int kv = unit & 3, rid = unit >> 2;
        const int b = rid >> 12, pos = rid & 4095;
        const float* src = ctxk + ((size_t)rid * 4 + kv) * 128;
        float2 xa = *(const float2*)(src + 2 * j);
        float2 xb = *(const float2*)(src + 2 * j + 64);
        norm_rope_vals(xa, xb, kw, cosT, sinT, pos, j, 1.0f,
                       Kb + ((size_t)(b * 4 + kv) * TTOT + pos) * 128);
    } else if (bid < 18432) {
        // ---- ctx V^T ----
        const int i = bid - 16384;
        const int pt = i & 63, kv = (i >> 6) & 3, b = i >> 8;
        const int t = threadIdx.x;
        const int d = t & 127, half = t >> 7;
        const int p0 = pt * 64 + half * 32;
        u16* dst = VtG + ((size_t)(b * 4 + kv) * 128 + d) * TTOT + p0;
        const float* src = ctxv + ((size_t)(b * 4096 + p0) * 4 + kv) * 128 + d;
#pragma unroll
        for (int j8 = 0; j8 < 4; ++j8) {
            s16x8 v;
#pragma unroll
            for (int je = 0; je < 8; ++je)
                v[je] = (short)f2bf(src[(size_t)(j8 * 8 + je) * 512]);
            *(s16x8*)(dst + j8 * 8) = v;
        }
    } else if (bid < 18464) {
        // ---- knb -> Kb rows 4096..4159 (contiguous copy, 16 KB/block) ----
        const int idx = bid - 18432;   // b*4+kv
        const u16* src = knb + (size_t)idx * 64 * 128;
        u16* dst = Kb + ((size_t)idx * TTOT + 4096) * 128;
#pragma unroll
        for (int it = 0; it < 4; ++it) {
            const int e = (it * 256 + threadIdx.x) * 8;
            *(s16x8*)(dst + e) = *(const s16x8*)(src + e);
        }
    } else {
        // ---- vnb -> VtG cols 4096..4159 (64x128 transpose) ----
        const int idx = bid - 18464;   // b*4+kv
        const u16* src = vnb + (size_t)idx * 64 * 128;
        u16* dstb = VtG + (size_t)idx * 128 * TTOT + 4096;
        const int d = threadIdx.x & 127, qh = threadIdx.x >> 7;
        u16* dst = dstb + (size_t)d * TTOT + qh * 32;
#pragma unroll
        for (int q8 = 0; q8 < 4; ++q8) {
            s16x8 v;
#pragma unroll
            for (int je = 0; je < 8; ++je)
                v[je] = (short)src[(size_t)(qh * 32 + q8 * 8 + je) * 128 + d];
            *(s16x8*)(dst + q8 * 8) = v;
        }
    }
}

// ---------------- flash attention partial: pipelined double-buffer --------
// (round-6/9 proven: 1 block/CU, LDS 124 KB, loads never in flight at
// barrier, setprio around MFMA clusters)
template <int S>
__global__ __launch_bounds__(512, 2) void attn_partial(
    const u16* __restrict__ Qb, const u16* __restrict__ Kb, const u16* __restrict__ VtG,
    const float* __restrict__ mask, u16* __restrict__ Opart, float* __restrict__ lsum)
{
    __shared__ __align__(16) u16   Ksh[2][64 * 136];   // K [pos][d], padded
    __shared__ __align__(16) u16   Vsh[2][128 * 72];   // V^T [d][pos], padded
    __shared__ __align__(16) float Msh[2][64 * 68];    // mask*log2e - MFIX
    __shared__ __align__(16) u16   Psh[8][32 * 40];    // per-wave P chunk

    const int s = blockIdx.x, kv = blockIdx.y, b = blockIdx.z;
    const int tid = threadIdx.x, lane = tid & 63, w = tid >> 6;
    const int h = kv * 4 + (w >> 1);
    const int qh = w & 1, qbase = qh * 32;
    const int l15 = lane & 15, l4 = lane >> 4;
    const int t0 = (NTILES * s) / S, t1 = (NTILES * (s + 1)) / S;

    bf16x8 aq[2][4];
    {
        const u16* qb = Qb + ((size_t)((b * 16 + h) * 64 + qbase)) * 128;
#pragma unroll
        for (int mt = 0; mt < 2; ++mt)
#pragma unroll
            for (int ks = 0; ks < 4; ++ks)
                aq[mt][ks] = *(const bf16x8*)(qb + (mt * 16 + l15) * 128 + ks * 32 + l4 * 8);
    }

    bf16x8 bones;   // col-0 ones -> P row sums via MFMA
    {
        __bf16 e = (l15 == 0) ? (__bf16)1.0f : (__bf16)0.0f;
#pragma unroll
        for (int i = 0; i < 8; ++i) bones[i] = e;
    }

    f32x4 o[2][8], ol[2];
#pragma unroll
    for (int mt = 0; mt < 2; ++mt) {
        ol[mt] = (f32x4){0.f, 0.f, 0.f, 0.f};
#pragma unroll
        for (int nt = 0; nt < 8; ++nt) o[mt][nt] = (f32x4){0.f, 0.f, 0.f, 0.f};
    }

    const u16* Kbase = Kb + (size_t)(b * 4 + kv) * TTOT * 128;
    const u16* Vbase = VtG + (size_t)(b * 4 + kv) * 128 * TTOT;
    const float* mrow = mask + (size_t)b * 64 * TTOT;
    u16* P = Psh[w];

    const int kp = tid >> 4, kd8 = (tid & 15) * 8;   // K rows kp, kp+32
    const int vr = tid >> 3, vc8 = (tid & 7) * 8;    // V rows vr, vr+64
    const int mq_ = tid >> 3, mk8 = (tid & 7) * 8;   // mask row, col block

    s16x8 rk0, rk1, rv0, rv1;
    float4 rm0, rm1;

    auto ld = [&](int t) {
        const int p = t * 64;
        rk0 = *(const s16x8*)(Kbase + (size_t)(p + kp) * 128 + kd8);
        rk1 = *(const s16x8*)(Kbase + (size_t)(p + kp + 32) * 128 + kd8);
        rv0 = *(const s16x8*)(Vbase + (size_t)vr * TTOT + p + vc8);
        rv1 = *(const s16x8*)(Vbase + (size_t)(vr + 64) * TTOT + p + vc8);
        const float* mp = mrow + (size_t)mq_ * TTOT + p + mk8;
        rm0 = *(const float4*)mp;
        rm1 = *(const float4*)(mp + 4);
        __builtin_amdgcn_sched_barrier(0);   // pin load issue here
    };
    auto st = [&](int buf) {
        *(s16x8*)(Ksh[buf] + kp * 136 + kd8) = rk0;
        *(s16x8*)(Ksh[buf] + (kp + 32) * 136 + kd8) = rk1;
        *(s16x8*)(Vsh[buf] + vr * 72 + vc8) = rv0;
        *(s16x8*)(Vsh[buf] + (vr + 64) * 72 + vc8) = rv1;
        float* md = Msh[buf] + mq_ * 68 + mk8;
        md[0] = fmaf(rm0.x, LOG2E, -MFIX); md[1] = fmaf(rm0.y, LOG2E, -MFIX);
        md[2] = fmaf(rm0.z, LOG2E, -MFIX); md[3] = fmaf(rm0.w, LOG2E, -MFIX);
        md[4] = fmaf(rm1.x, LOG2E, -MFIX); md[5] = fmaf(rm1.y, LOG2E, -MFIX);
        md[6] = fmaf(rm1.z, LOG2E, -MFIX); md[7] = fmaf(rm1.w, LOG2E, -MFIX);
    };

    // prologue
    ld(t0);
    st(0);
    __syncthreads();
    if (t0 + 1 < t1) ld(t0 + 1);

    int cur = 0;
    for (int t = t0; t < t1; ++t) {
        // ---- compute tile t from buf[cur] ----
        f32x4 sc[2][4];
#pragma unroll
        for (int mt = 0; mt < 2; ++mt)
#pragma unroll
            for (int nt = 0; nt < 4; ++nt) sc[mt][nt] = (f32x4){0.f, 0.f, 0.f, 0.f};
        __builtin_amdgcn_s_setprio(1);
#pragma unroll
        for (int nt = 0; nt < 4; ++nt) {
#pragma unroll
            for (int ks = 0; ks < 4; ++ks) {
                bf16x8 bk = *(const bf16x8*)(Ksh[cur] + (nt * 16 + l15) * 136 + ks * 32 + l4 * 8);
                sc[0][nt] = mfma16(aq[0][ks], bk, sc[0][nt]);
                sc[1][nt] = mfma16(aq[1][ks], bk, sc[1][nt]);
            }
        }
        __builtin_amdgcn_s_setprio(0);

        // fixed-max softmax: p = exp2(sc + msh), msh = mask*log2e - MFIX
#pragma unroll
        for (int mt = 0; mt < 2; ++mt) {
#pragma unroll
            for (int r = 0; r < 4; ++r) {
                const int q = qbase + mt * 16 + l4 * 4 + r;
                const float* mq = Msh[cur] + q * 68 + l15;
                sc[mt][0][r] = exp2f(sc[mt][0][r] + mq[0]);
                sc[mt][1][r] = exp2f(sc[mt][1][r] + mq[16]);
                sc[mt][2][r] = exp2f(sc[mt][2][r] + mq[32]);
                sc[mt][3][r] = exp2f(sc[mt][3][r] + mq[48]);
            }
        }

        // O += P V ; l += P 1
#pragma unroll
        for (int ks = 0; ks < 2; ++ks) {
#pragma unroll
            for (int mt = 0; mt < 2; ++mt)
#pragma unroll
                for (int r = 0; r < 4; ++r) {
                    P[(mt * 16 + l4 * 4 + r) * 40 + l15]      = f2bf(sc[mt][ks * 2 + 0][r]);
                    P[(mt * 16 + l4 * 4 + r) * 40 + 16 + l15] = f2bf(sc[mt][ks * 2 + 1][r]);
                }
            bf16x8 ap0 = *(const bf16x8*)(P + (l15) * 40 + l4 * 8);
            bf16x8 ap1 = *(const bf16x8*)(P + (16 + l15) * 40 + l4 * 8);
            __builtin_amdgcn_s_setprio(1);
#pragma unroll
            for (int nt = 0; nt < 8; ++nt) {
                bf16x8 bv = *(const bf16x8*)(Vsh[cur] + (nt * 16 + l15) * 72 + ks * 32 + l4 * 8);
                o[0][nt] = mfma16(ap0, bv, o[0][nt]);
                o[1][nt] = mfma16(ap1, bv, o[1][nt]);
            }
            ol[0] = mfma16(ap0, bones, ol[0]);
            ol[1] = mfma16(ap1, bones, ol[1]);
            __builtin_amdgcn_s_setprio(0);
        }

        // ---- stage tile t+1 into buf[cur^1]; prefetch t+2 ----
        if (t + 1 < t1) st(cur ^ 1);      // waits vmcnt for ld(t+1) regs here
        __syncthreads();                  // vmcnt already 0: no drain cost
        if (t + 2 < t1) ld(t + 2);        // in flight across next compute
        cur ^= 1;
    }

    // coalesced epilogue: Opart chunk per (b,h,s) = [qh][mt][nt][lane][r] u16
    {
        u16* ob = Opart + ((size_t)((b * 16 + h) * S + s)) * 8192;
#pragma unroll
        for (int mt = 0; mt < 2; ++mt)
#pragma unroll
            for (int nt = 0; nt < 8; ++nt) {
                u16x4 v;
#pragma unroll
                for (int r = 0; r < 4; ++r) v[r] = f2bf(o[mt][nt][r]);
                *(u16x4*)(ob + (((qh * 2 + mt) * 8 + nt) * 64 + lane) * 4) = v;
            }
        if (l15 == 0) {
#pragma unroll
            for (int mt = 0; mt < 2; ++mt)
#pragma unroll
                for (int r = 0; r < 4; ++r) {
                    const int q = qbase + mt * 16 + l4 * 4 + r;
                    lsum[((size_t)((b * 16 + h) * 64 + q)) * S + s] = ol[mt][r];
                }
        }
    }
}

// ---------------- merge splits -> attn (B,K,NH*HD) bf16 -------------------
template <int S>
__global__ __launch_bounds__(256) void merge_kernel(
    const u16* __restrict__ Opart, const float* __restrict__ lsum, u16* __restrict__ attnb)
{
    const int wid = blockIdx.x * 4 + (threadIdx.x >> 6);   // (b*16+h)*2 + qh
    const int lane = threadIdx.x & 63;
    const int l15 = lane & 15, l4 = lane >> 4;
    const int qh = wid & 1, bh = wid >> 1;
    const int h = bh & 15, b = bh >> 4;

    float L = 0.f;
    {
        const float* lr = lsum + ((size_t)bh * 64 + qh * 32 + (lane & 31)) * S;
#pragma unroll
        for (int s2 = 0; s2 < S; ++s2) L += lr[s2];
    }
    const float invL = 1.0f / L;

    float acc[2][8][4];
#pragma unroll
    for (int mt = 0; mt < 2; ++mt)
#pragma unroll
        for (int nt = 0; nt < 8; ++nt)
#pragma unroll
            for (int r = 0; r < 4; ++r) acc[mt][nt][r] = 0.f;

    for (int s2 = 0; s2 < S; ++s2) {
        const u16* ob = Opart + ((size_t)(bh * S + s2)) * 8192;
#pragma unroll
        for (int mt = 0; mt < 2; ++mt)
#pragma unroll
            for (int nt = 0; nt < 8; ++nt) {
                u16x4 v = *(const u16x4*)(ob + (((qh * 2 + mt) * 8 + nt) * 64 + lane) * 4);
#pragma unroll
                for (int r = 0; r < 4; ++r) acc[mt][nt][r] += bf2f(v[r]);
            }
    }

#pragma unroll
    for (int mt = 0; mt < 2; ++mt)
#pragma unroll
        for (int r = 0; r < 4; ++r) {
            const float wl = __shfl(invL, mt * 16 + l4 * 4 + r);
            const int q = qh * 32 + mt * 16 + l4 * 4 + r;
            u16* dst = attnb + (size_t)(b * 64 + q) * 2048 + h * 128;
#pragma unroll
            for (int nt = 0; nt < 8; ++nt)
                dst[nt * 16 + l15] = f2bf(acc[mt][nt][r] * wl);
        }
}

// ---------------- launch ----------------
extern "C" void kernel_launch(void* const* d_in, const int* in_sizes, int n_in,
                              void* d_out, int out_size, void* d_ws, size_t ws_size,
                              hipStream_t stream)
{
    (void)in_sizes; (void)n_in; (void)out_size; (void)ws_size;
    const float* hs   = (const float*)d_in[0];
    const float* ctxk = (const float*)d_in[1];
    const float* ctxv = (const float*)d_in[2];
    const float* mask = (const float*)d_in[3];
    const float* cosT = (const float*)d_in[4];
    const float* sinT = (const float*)d_in[5];
    const float* wq   = (const float*)d_in[6];
    const float* wk   = (const float*)d_in[7];
    const float* wv   = (const float*)d_in[8];
    const float* wo   = (const float*)d_in[9];
    const float* qnw  = (const float*)d_in[10];
    const float* knw  = (const float*)d_in[11];

    const int S = 8;

    char* ws = (char*)d_ws;
    size_t off = 0;
    auto carve = [&](size_t bytes) -> void* {
        void* p = ws + off;
        off += (bytes + 255) & ~(size_t)255;
        return p;
    };
    u16*   Qb    = (u16*)carve((size_t)BB * NH * 64 * 128 * 2);         // 2.1 MB
    u16*   Kb    = (u16*)carve((size_t)BB * NKV * TTOT * 128 * 2);      // 34.1 MB
    u16*   VtG   = (u16*)carve((size_t)BB * NKV * TTOT * 128 * 2);      // 34.1 MB
    u16*   Opart = (u16*)carve((size_t)BB * NH * S * 8192 * 2);         // 16.8 MB
    float* lsumb = (float*)carve((size_t)BB * NH * 64 * S * 4);         // 0.26 MB
    u16*   attnb = (u16*)carve((size_t)512 * 2048 * 2);                 // 2.1 MB
    u16*   wob   = (u16*)carve((size_t)2048 * 2048 * 2);                // 8.4 MB
    u16*   knb   = (u16*)carve((size_t)BB * NKV * 64 * 128 * 2);        // 0.52 MB
    u16*   vnb   = (u16*)carve((size_t)BB * NKV * 64 * 128 * 2);        // 0.52 MB
    // ~99 MB. Time-multiplexed aliases (stream-ordered liveness):
    u16*   wqkvb = (u16*)Kb;     // bf16 qkv weights; dead before build_ctx
    float* qkvp  = (float*)VtG;  // qkv split-K partials; dead before build_ctx
    u16*   hsb   = (u16*)Opart;  // bf16 hs; dead before attn_partial
    float* outp  = (float*)Kb;   // out partials; Kb dead after attn_partial

    // 1) one fused cast of all weights + activations to bf16
    cast_all<<<5632, 256, 0, stream>>>(wq, wk, wv, wo, hs, wqkvb, wob, hsb);
    // 2) QKV projection (bf16, split-K x4, XCD swizzle)
    gemm_qkv_sk<<<1536, 256, 0, stream>>>(hsb, wqkvb, qkvp);
    // 3) fused reduce + RMSNorm/RoPE/cast -> Qb, k-noise, v-noise
    finalize_qkv<<<1536, 256, 0, stream>>>(qkvp, qnw, knw, cosT, sinT, Qb, knb, vnb);
    // 4) fused ctx K + ctx V^T + noise scatter
    build_ctx<<<18496, 256, 0, stream>>>(ctxk, knw, cosT, sinT, ctxv, knb, vnb, Kb, VtG);
    // 5) flash attention + merge (attnb in bf16 for the out-proj)
    attn_partial<8><<<dim3(8, NKV, BB), 512, 0, stream>>>(Qb, Kb, VtG, mask, Opart, lsumb);
    merge_kernel<8><<<64, 256, 0, stream>>>(Opart, lsumb, attnb);
    // 6) output projection (bf16, split-K x4, XCD swizzle) -> reduce
    gemm_out_sk<<<1024, 256, 0, stream>>>(attnb, wob, outp);
    reduce4<<<1024, 256, 0, stream>>>(outp, (float*)d_out, (size_t)512 * 2048);
}

// Round 11
// 139.951 us; speedup vs baseline: 1.2953x; 1.0401x over previous
//
#include <hip/hip_runtime.h>

// ---------------- problem constants ----------------
#define BB   8
#define KQ   64
#define HDIM 2048
#define NH   16
#define NKV  4
#define HD   128
#define CTX  4096
#define TTOT 4160      // CTX + KQ
#define NTILES 65      // TTOT / 64
#define LOG2E 1.4426950408889634f
#define SCALE 0.08838834764831845f  // 1/sqrt(128)
#define QSCALE (SCALE * LOG2E)      // folded into Q; exp2-domain softmax
// |q.k| <= 128 after RMS-norm => |sc| <= 128*QSCALE = 16.33. Fixed softmax max.
#define MFIX 16.34f

typedef unsigned short u16;
typedef unsigned int   u32;
typedef __attribute__((ext_vector_type(8))) short  s16x8;   // bf16 storage
typedef __attribute__((ext_vector_type(4))) unsigned short u16x4;
typedef __attribute__((ext_vector_type(4))) float  f32x4;
typedef __bf16 bf16x8 __attribute__((ext_vector_type(8)));  // MFMA operand

__device__ __forceinline__ u16 f2bf(float f) {              // HW RNE cvt
    union { __bf16 h; u16 u; } v; v.h = (__bf16)f; return v.u;
}
__device__ __forceinline__ float bf2f(u16 u) {
    union { float f; u32 u; } v; v.u = ((u32)u) << 16;
    return v.f;
}
__device__ __forceinline__ u32 pack2(float a, float b) {
    return (u32)f2bf(a) | ((u32)f2bf(b) << 16);
}
__device__ __forceinline__ f32x4 mfma16(bf16x8 a, bf16x8 b, f32x4 c) {
    return __builtin_amdgcn_mfma_f32_16x16x32_bf16(a, b, c, 0, 0, 0);
}

// ---------------- fused f32 -> bf16 cast of all 5 tensors -----------------
__global__ __launch_bounds__(256) void cast_all(
    const float* __restrict__ wq, const float* __restrict__ wk,
    const float* __restrict__ wv, const float* __restrict__ wo,
    const float* __restrict__ hs,
    u16* __restrict__ wqkvb, u16* __restrict__ wob, u16* __restrict__ hsb)
{
    const int i = blockIdx.x * 256 + threadIdx.x;
    const float* src; u16* dst;
    if (i < 524288)       { src = wq + (size_t)i * 8;             dst = wqkvb + (size_t)i * 8; }
    else if (i < 655360)  { src = wk + (size_t)(i - 524288) * 8;  dst = wqkvb + (size_t)i * 8; }
    else if (i < 786432)  { src = wv + (size_t)(i - 655360) * 8;  dst = wqkvb + (size_t)i * 8; }
    else if (i < 1310720) { src = wo + (size_t)(i - 786432) * 8;  dst = wob + (size_t)(i - 786432) * 8; }
    else                  { src = hs + (size_t)(i - 1310720) * 8; dst = hsb + (size_t)(i - 1310720) * 8; }
    float4 a = *(const float4*)src;
    float4 b = *(const float4*)(src + 4);
    s16x8 v;
    v[0]=(short)f2bf(a.x); v[1]=(short)f2bf(a.y); v[2]=(short)f2bf(a.z); v[3]=(short)f2bf(a.w);
    v[4]=(short)f2bf(b.x); v[5]=(short)f2bf(b.y); v[6]=(short)f2bf(b.z); v[7]=(short)f2bf(b.w);
    *(s16x8*)dst = v;
}

// ---------------- 64x64-tile GEMM core, bf16 inputs (padded LDS) ----------
__device__ __forceinline__ void gemm64_body(
    const u16* __restrict__ Ab, const u16* __restrict__ Bb,
    float* __restrict__ Cb, const int ldc, const int ldk, const int Klen,
    u16* Ash, u16* Bsh)
{
    const int tid = threadIdx.x, lane = tid & 63;
    const int w = tid >> 6, wm = w >> 1, wn = w & 1;
    const int l15 = lane & 15, l4 = lane >> 4;
    const int srow = tid >> 2, scol = (tid & 3) * 16;

    f32x4 acc[2][2];
#pragma unroll
    for (int i = 0; i < 2; ++i)
#pragma unroll
        for (int j = 0; j < 2; ++j) acc[i][j] = (f32x4){0.f, 0.f, 0.f, 0.f};

    const u16* ap = Ab + (size_t)srow * ldk + scol;
    const u16* bp = Bb + (size_t)srow * ldk + scol;
    s16x8 ra0 = *(const s16x8*)ap, ra1 = *(const s16x8*)(ap + 8);
    s16x8 rb0 = *(const s16x8*)bp, rb1 = *(const s16x8*)(bp + 8);
    __builtin_amdgcn_sched_barrier(0);

    for (int k0 = 0; k0 < Klen; k0 += 64) {
        __syncthreads();
        *(s16x8*)(Ash + srow * 72 + scol)     = ra0;
        *(s16x8*)(Ash + srow * 72 + scol + 8) = ra1;
        *(s16x8*)(Bsh + srow * 72 + scol)     = rb0;
        *(s16x8*)(Bsh + srow * 72 + scol + 8) = rb1;
        __syncthreads();
        if (k0 + 64 < Klen) {
            const u16* ap2 = ap + k0 + 64;
            const u16* bp2 = bp + k0 + 64;
            ra0 = *(const s16x8*)ap2; ra1 = *(const s16x8*)(ap2 + 8);
            rb0 = *(const s16x8*)bp2; rb1 = *(const s16x8*)(bp2 + 8);
            __builtin_amdgcn_sched_barrier(0);
        }
#pragma unroll
        for (int ks = 0; ks < 2; ++ks) {
            bf16x8 am[2], bb[2];
#pragma unroll
            for (int i = 0; i < 2; ++i) {
                am[i] = *(const bf16x8*)(Ash + (wm * 32 + i * 16 + l15) * 72 + ks * 32 + l4 * 8);
                bb[i] = *(const bf16x8*)(Bsh + (wn * 32 + i * 16 + l15) * 72 + ks * 32 + l4 * 8);
            }
#pragma unroll
            for (int i = 0; i < 2; ++i)
#pragma unroll
                for (int j = 0; j < 2; ++j)
                    acc[i][j] = mfma16(am[i], bb[j], acc[i][j]);
        }
    }

    float* Cw = Cb + (size_t)(wm * 32) * ldc + wn * 32;
#pragma unroll
    for (int i = 0; i < 2; ++i)
#pragma unroll
        for (int j = 0; j < 2; ++j)
#pragma unroll
            for (int r = 0; r < 4; ++r)
                Cw[(size_t)(i * 16 + l4 * 4 + r) * ldc + j * 16 + l15] = acc[i][j][r];
}

// QKV projection, split-K x4, XCD-chunked swizzle. 1D grid 1536.
__global__ __launch_bounds__(256) void gemm_qkv_sk(
    const u16* __restrict__ hsb, const u16* __restrict__ wqkvb,
    float* __restrict__ qkvp)
{
    __shared__ __align__(16) u16 Ash[64 * 72];
    __shared__ __align__(16) u16 Bsh[64 * 72];
    const int wid = (blockIdx.x & 7) * 192 + (blockIdx.x >> 3);
    const int y = wid >> 5, rem = wid & 31, kc = rem >> 3, x = rem & 7;
    const int koff = kc * 512;
    const u16* Ab = hsb + (size_t)x * 64 * HDIM + koff;
    const u16* Bb = wqkvb + (size_t)y * 64 * HDIM + koff;
    float* Cb = qkvp + (size_t)kc * 512 * 3072 + (size_t)x * 64 * 3072 + y * 64;
    gemm64_body(Ab, Bb, Cb, 3072, HDIM, 512, Ash, Bsh);
}

// Output projection, split-K x4, XCD-chunked swizzle. 1D grid 1024.
__global__ __launch_bounds__(256) void gemm_out_sk(
    const u16* __restrict__ attnb, const u16* __restrict__ wob,
    float* __restrict__ outp)
{
    __shared__ __align__(16) u16 Ash[64 * 72];
    __shared__ __align__(16) u16 Bsh[64 * 72];
    const int wid = (blockIdx.x & 7) * 128 + (blockIdx.x >> 3);
    const int y = wid >> 5, rem = wid & 31, kc = rem >> 3, x = rem & 7;
    const int koff = kc * 512;
    const u16* Ab = attnb + (size_t)x * 64 * HDIM + koff;
    const u16* Bb = wob + (size_t)y * 64 * HDIM + koff;
    float* Cb = outp + (size_t)kc * 512 * 2048 + (size_t)x * 64 * 2048 + y * 64;
    gemm64_body(Ab, Bb, Cb, 2048, HDIM, 512, Ash, Bsh);
}

// sum 4 partial chunks -> out (float4 per thread), deterministic.
__global__ __launch_bounds__(256) void reduce4(
    const float* __restrict__ p, float* __restrict__ out, const size_t chunk)
{
    const size_t i = ((size_t)blockIdx.x * 256 + threadIdx.x) * 4;
    float4 a = *(const float4*)(p + i);
    float4 b = *(const float4*)(p + i + chunk);
    float4 c = *(const float4*)(p + i + 2 * chunk);
    float4 d = *(const float4*)(p + i + 3 * chunk);
    float4 r;
    r.x = (a.x + b.x) + (c.x + d.x);
    r.y = (a.y + b.y) + (c.y + d.y);
    r.z = (a.z + b.z) + (c.z + d.z);
    r.w = (a.w + b.w) + (c.w + d.w);
    *(float4*)(out + i) = r;
}

// ---------------- RMSNorm+RoPE on in-register values (half-wave) ----------
// cos/sin tables have duplicated halves (emb = concat(freqs, freqs)):
// cos[pos][d+64] == cos[pos][d] -> load only the low half.
__device__ __forceinline__ void norm_rope_vals(
    float2 xa, float2 xb, const float* __restrict__ wgt,
    const float* __restrict__ cosT, const float* __restrict__ sinT,
    int pos, int j, float outScale, u16* __restrict__ dst)
{
    float ss = xa.x * xa.x + xa.y * xa.y + xb.x * xb.x + xb.y * xb.y;
#pragma unroll
    for (int m = 1; m < 32; m <<= 1) ss += __shfl_xor(ss, m);
    const float rr = rsqrtf(ss * (1.0f / 128.0f) + 1e-6f);
    float2 wa = *(const float2*)(wgt + 2 * j);
    float2 wb = *(const float2*)(wgt + 2 * j + 64);
    float2 ca = *(const float2*)(cosT + (size_t)pos * 128 + 2 * j);
    float2 sa = *(const float2*)(sinT + (size_t)pos * 128 + 2 * j);
    const float nax = xa.x * rr * wa.x, nay = xa.y * rr * wa.y;
    const float nbx = xb.x * rr * wb.x, nby = xb.y * rr * wb.y;
    const float lox = (nax * ca.x - nbx * sa.x) * outScale;
    const float loy = (nay * ca.y - nby * sa.y) * outScale;
    const float hix = (nbx * ca.x + nax * sa.x) * outScale;
    const float hiy = (nby * ca.y + nay * sa.y) * outScale;
    ((u32*)dst)[j]      = pack2(lox, loy);
    ((u32*)dst)[j + 32] = pack2(hix, hiy);
}

// ---------------- fused split-K reduce + RMSNorm/RoPE/cast ----------------
// slot: 0..15 q heads -> Qb; 16..19 k-noise -> knb; 20..23 v-noise -> vnb.
__global__ __launch_bounds__(256) void finalize_qkv(
    const float* __restrict__ qkvp, const float* __restrict__ qw,
    const float* __restrict__ kw, const float* __restrict__ cosT,
    const float* __restrict__ sinT,
    u16* __restrict__ Qb, u16* __restrict__ knb, u16* __restrict__ vnb)
{
    const int unit = blockIdx.x * 8 + (threadIdx.x >> 5);
    const int j = threadIdx.x & 31;
    const int slot = unit % 24, bq = unit / 24;
    const int b = bq >> 6, q = bq & 63;
    const int col0 = (slot < 16) ? slot * 128
                   : (slot < 20) ? 2048 + (slot - 16) * 128
                                 : 2560 + (slot - 20) * 128;
    const float* base = qkvp + (size_t)bq * 3072 + col0;

    float2 xa = {0.f, 0.f}, xb = {0.f, 0.f};
#pragma unroll
    for (int kc = 0; kc < 4; ++kc) {
        const float* p = base + (size_t)kc * 512 * 3072;
        float2 a = *(const float2*)(p + 2 * j);
        float2 c = *(const float2*)(p + 2 * j + 64);
        xa.x += a.x; xa.y += a.y; xb.x += c.x; xb.y += c.y;
    }

    if (slot < 16) {
        norm_rope_vals(xa, xb, qw, cosT, sinT, CTX + q, j, QSCALE,
                       Qb + ((size_t)((b * 16 + slot) * 64 + q)) * 128);
    } else if (slot < 20) {
        norm_rope_vals(xa, xb, kw, cosT, sinT, CTX + q, j, 1.0f,
                       knb + ((size_t)((b * 4 + (slot - 16)) * 64 + q)) * 128);
    } else {
        u16* dst = vnb + ((size_t)((b * 4 + (slot - 20)) * 64 + q)) * 128;
        ((u32*)dst)[j]      = pack2(xa.x, xa.y);
        ((u32*)dst)[j + 32] = pack2(xb.x, xb.y);
    }
}

// ---------------- fused ctx build: K norm+rope, V^T, noise scatter --------
// blocks [0,4096): ctx K — half-wave per (b,pos), kv x4 INTERLEAVED:
//   shared cos/sin/w loads, 4 independent reduce chains in flight (the
//   round-10 version ran 1 chain/half-wave and was latency-bound at 2.1TB/s).
// [4096,6144): ctx V^T tiles. [6144,6176): knb copy. [6176,6208): vnb^T.
__global__ __launch_bounds__(256) void build_ctx(
    const float* __restrict__ ctxk, const float* __restrict__ kw,
    const float* __restrict__ cosT, const float* __restrict__ sinT,
    const float* __restrict__ ctxv, const u16* __restrict__ knb,
    const u16* __restrict__ vnb, u16* __restrict__ Kb, u16* __restrict__ VtG)
{
    const int bid = blockIdx.x;
    if (bid < 4096) {
        const int unit = bid * 8 + (threadIdx.x >> 5);   // b*4096 + pos
        const int j = threadIdx.x & 31;
        const int b = unit >> 12, pos = unit & 4095;
        float2 ca = *(const float2*)(cosT + (size_t)pos * 128 + 2 * j);
        float2 sa = *(const float2*)(sinT + (size_t)pos * 128 + 2 * j);
        float2 wa = *(const float2*)(kw + 2 * j);
        float2 wb = *(const float2*)(kw + 2 * j + 64);
        const float* src0 = ctxk + (size_t)unit * 512;   // 4 kv rows of 128
        float2 xa[4], xb[4];
#pragma unroll
        for (int kv = 0; kv < 4; ++kv) {
            xa[kv] = *(const float2*)(src0 + kv * 128 + 2 * j);
            xb[kv] = *(const float2*)(src0 + kv * 128 + 2 * j + 64);
        }
        float ss[4];
#pragma unroll
        for (int kv = 0; kv < 4; ++kv)
            ss[kv] = xa[kv].x * xa[kv].x + xa[kv].y * xa[kv].y
                   + xb[kv].x * xb[kv].x + xb[kv].y * xb[kv].y;
#pragma unroll
        for (int m = 1; m < 32; m <<= 1) {
#pragma unroll
            for (int kv = 0; kv < 4; ++kv) ss[kv] += __shfl_xor(ss[kv], m);
        }
#pragma unroll
        for (int kv = 0; kv < 4; ++kv) {
            const float rr = rsqrtf(ss[kv] * (1.0f / 128.0f) + 1e-6f);
            const float nax = xa[kv].x * rr * wa.x, nay = xa[kv].y * rr * wa.y;
            const float nbx = xb[kv].x * rr * wb.x, nby = xb[kv].y * rr * wb.y;
            u16* dst = Kb + ((size_t)(b * 4 + kv) * TTOT + pos) * 128;
            ((u32*)dst)[j]      = pack2(nax * ca.x - nbx * sa.x, nay * ca.y - nby * sa.y);
            ((u32*)dst)[j + 32] = pack2(nbx * ca.x + nax * sa.x, nby * ca.y + nay * sa.y);
        }
    } else if (bid < 6144) {
        // ---- ctx V^T ----
        const int i = bid - 4096;
        const int pt = i & 63, kv = (i >> 6) & 3, b = i >> 8;
        const int t = threadIdx.x;
        const int d = t & 127, half = t >> 7;
        const int p0 = pt * 64 + half * 32;
        u16* dst = VtG + ((size_t)(b * 4 + kv) * 128 + d) * TTOT + p0;
        const float* src = ctxv + ((size_t)(b * 4096 + p0) * 4 + kv) * 128 + d;
#pragma unroll
        for (int j8 = 0; j8 < 4; ++j8) {
            s16x8 v;
#pragma unroll
            for (int je = 0; je < 8; ++je)
                v[je] = (short)f2bf(src[(size_t)(j8 * 8 + je) * 512]);
            *(s16x8*)(dst + j8 * 8) = v;
        }
    } else if (bid < 6176) {
        // ---- knb -> Kb rows 4096..4159 (contiguous copy) ----
        const int idx = bid - 6144;   // b*4+kv
        const u16* src = knb + (size_t)idx * 64 * 128;
        u16* dst = Kb + ((size_t)idx * TTOT + 4096) * 128;
#pragma unroll
        for (int it = 0; it < 4; ++it) {
            const int e = (it * 256 + threadIdx.x) * 8;
            *(s16x8*)(dst + e) = *(const s16x8*)(src + e);
        }
    } else {
        // ---- vnb -> VtG cols 4096..4159 (64x128 transpose) ----
        const int idx = bid - 6176;   // b*4+kv
        const u16* src = vnb + (size_t)idx * 64 * 128;
        u16* dstb = VtG + (size_t)idx * 128 * TTOT + 4096;
        const int d = threadIdx.x & 127, qh = threadIdx.x >> 7;
        u16* dst = dstb + (size_t)d * TTOT + qh * 32;
#pragma unroll
        for (int q8 = 0; q8 < 4; ++q8) {
            s16x8 v;
#pragma unroll
            for (int je = 0; je < 8; ++je)
                v[je] = (short)src[(size_t)(qh * 32 + q8 * 8 + je) * 128 + d];
            *(s16x8*)(dst + q8 * 8) = v;
        }
    }
}

// ---------------- flash attention partial: pipelined double-buffer --------
template <int S>
__global__ __launch_bounds__(512, 2) void attn_partial(
    const u16* __restrict__ Qb, const u16* __restrict__ Kb, const u16* __restrict__ VtG,
    const float* __restrict__ mask, u16* __restrict__ Opart, float* __restrict__ lsum)
{
    __shared__ __align__(16) u16   Ksh[2][64 * 136];   // K [pos][d], padded
    __shared__ __align__(16) u16   Vsh[2][128 * 72];   // V^T [d][pos], padded
    __shared__ __align__(16) float Msh[2][64 * 68];    // mask*log2e - MFIX
    __shared__ __align__(16) u16   Psh[8][32 * 40];    // per-wave P chunk

    const int s = blockIdx.x, kv = blockIdx.y, b = blockIdx.z;
    const int tid = threadIdx.x, lane = tid & 63, w = tid >> 6;
    const int h = kv * 4 + (w >> 1);
    const int qh = w & 1, qbase = qh * 32;
    const int l15 = lane & 15, l4 = lane >> 4;
    const int t0 = (NTILES * s) / S, t1 = (NTILES * (s + 1)) / S;

    bf16x8 aq[2][4];
    {
        const u16* qb = Qb + ((size_t)((b * 16 + h) * 64 + qbase)) * 128;
#pragma unroll
        for (int mt = 0; mt < 2; ++mt)
#pragma unroll
            for (int ks = 0; ks < 4; ++ks)
                aq[mt][ks] = *(const bf16x8*)(qb + (mt * 16 + l15) * 128 + ks * 32 + l4 * 8);
    }

    bf16x8 bones;   // col-0 ones -> P row sums via MFMA
    {
        __bf16 e = (l15 == 0) ? (__bf16)1.0f : (__bf16)0.0f;
#pragma unroll
        for (int i = 0; i < 8; ++i) bones[i] = e;
    }

    f32x4 o[2][8], ol[2];
#pragma unroll
    for (int mt = 0; mt < 2; ++mt) {
        ol[mt] = (f32x4){0.f, 0.f, 0.f, 0.f};
#pragma unroll
        for (int nt = 0; nt < 8; ++nt) o[mt][nt] = (f32x4){0.f, 0.f, 0.f, 0.f};
    }

    const u16* Kbase = Kb + (size_t)(b * 4 + kv) * TTOT * 128;
    const u16* Vbase = VtG + (size_t)(b * 4 + kv) * 128 * TTOT;
    const float* mrow = mask + (size_t)b * 64 * TTOT;
    u16* P = Psh[w];

    const int kp = tid >> 4, kd8 = (tid & 15) * 8;   // K rows kp, kp+32
    const int vr = tid >> 3, vc8 = (tid & 7) * 8;    // V rows vr, vr+64
    const int mq_ = tid >> 3, mk8 = (tid & 7) * 8;   // mask row, col block

    s16x8 rk0, rk1, rv0, rv1;
    float4 rm0, rm1;

    auto ld = [&](int t) {
        const int p = t * 64;
        rk0 = *(const s16x8*)(Kbase + (size_t)(p + kp) * 128 + kd8);
        rk1 = *(const s16x8*)(Kbase + (size_t)(p + kp + 32) * 128 + kd8);
        rv0 = *(const s16x8*)(Vbase + (size_t)vr * TTOT + p + vc8);
        rv1 = *(const s16x8*)(Vbase + (size_t)(vr + 64) * TTOT + p + vc8);
        const float* mp = mrow + (size_t)mq_ * TTOT + p + mk8;
        rm0 = *(const float4*)mp;
        rm1 = *(const float4*)(mp + 4);
        __builtin_amdgcn_sched_barrier(0);   // pin load issue here
    };
    auto st = [&](int buf) {
        *(s16x8*)(Ksh[buf] + kp * 136 + kd8) = rk0;
        *(s16x8*)(Ksh[buf] + (kp + 32) * 136 + kd8) = rk1;
        *(s16x8*)(Vsh[buf] + vr * 72 + vc8) = rv0;
        *(s16x8*)(Vsh[buf] + (vr + 64) * 72 + vc8) = rv1;
        float* md = Msh[buf] + mq_ * 68 + mk8;
        md[0] = fmaf(rm0.x, LOG2E, -MFIX); md[1] = fmaf(rm0.y, LOG2E, -MFIX);
        md[2] = fmaf(rm0.z, LOG2E, -MFIX); md[3] = fmaf(rm0.w, LOG2E, -MFIX);
        md[4] = fmaf(rm1.x, LOG2E, -MFIX); md[5] = fmaf(rm1.y, LOG2E, -MFIX);
        md[6] = fmaf(rm1.z, LOG2E, -MFIX); md[7] = fmaf(rm1.w, LOG2E, -MFIX);
    };

    // prologue
    ld(t0);
    st(0);
    __syncthreads();
    if (t0 + 1 < t1) ld(t0 + 1);

    int cur = 0;
    for (int t = t0; t < t1; ++t) {
        // ---- compute tile t from buf[cur] ----
        f32x4 sc[2][4];
#pragma unroll
        for (int mt = 0; mt < 2; ++mt)
#pragma unroll
            for (int nt = 0; nt < 4; ++nt) sc[mt][nt] = (f32x4){0.f, 0.f, 0.f, 0.f};
        __builtin_amdgcn_s_setprio(1);
#pragma unroll
        for (int nt = 0; nt < 4; ++nt) {
#pragma unroll
            for (int ks = 0; ks < 4; ++ks) {
                bf16x8 bk = *(const bf16x8*)(Ksh[cur] + (nt * 16 + l15) * 136 + ks * 32 + l4 * 8);
                sc[0][nt] = mfma16(aq[0][ks], bk, sc[0][nt]);
                sc[1][nt] = mfma16(aq[1][ks], bk, sc[1][nt]);
            }
        }
        __builtin_amdgcn_s_setprio(0);

        // fixed-max softmax: p = exp2(sc + msh), msh = mask*log2e - MFIX
#pragma unroll
        for (int mt = 0; mt < 2; ++mt) {
#pragma unroll
            for (int r = 0; r < 4; ++r) {
                const int q = qbase + mt * 16 + l4 * 4 + r;
                const float* mq = Msh[cur] + q * 68 + l15;
                sc[mt][0][r] = exp2f(sc[mt][0][r] + mq[0]);
                sc[mt][1][r] = exp2f(sc[mt][1][r] + mq[16]);
                sc[mt][2][r] = exp2f(sc[mt][2][r] + mq[32]);
                sc[mt][3][r] = exp2f(sc[mt][3][r] + mq[48]);
            }
        }

        // O += P V ; l += P 1
#pragma unroll
        for (int ks = 0; ks < 2; ++ks) {
#pragma unroll
            for (int mt = 0; mt < 2; ++mt)
#pragma unroll
                for (int r = 0; r < 4; ++r) {
                    P[(mt * 16 + l4 * 4 + r) * 40 + l15]      = f2bf(sc[mt][ks * 2 + 0][r]);
                    P[(mt * 16 + l4 * 4 + r) * 40 + 16 + l15] = f2bf(sc[mt][ks * 2 + 1][r]);
                }
            bf16x8 ap0 = *(const bf16x8*)(P + (l15) * 40 + l4 * 8);
            bf16x8 ap1 = *(const bf16x8*)(P + (16 + l15) * 40 + l4 * 8);
            __builtin_amdgcn_s_setprio(1);
#pragma unroll
            for (int nt = 0; nt < 8; ++nt) {
                bf16x8 bv = *(const bf16x8*)(Vsh[cur] + (nt * 16 + l15) * 72 + ks * 32 + l4 * 8);
                o[0][nt] = mfma16(ap0, bv, o[0][nt]);
                o[1][nt] = mfma16(ap1, bv, o[1][nt]);
            }
            ol[0] = mfma16(ap0, bones, ol[0]);
            ol[1] = mfma16(ap1, bones, ol[1]);
            __builtin_amdgcn_s_setprio(0);
        }

        // ---- stage tile t+1 into buf[cur^1]; prefetch t+2 ----
        if (t + 1 < t1) st(cur ^ 1);      // waits vmcnt for ld(t+1) regs here
        __syncthreads();                  // vmcnt already 0: no drain cost
        if (t + 2 < t1) ld(t + 2);        // in flight across next compute
        cur ^= 1;
    }

    // coalesced epilogue: Opart chunk per (b,h,s) = [qh][mt][nt][lane][r] u16
    {
        u16* ob = Opart + ((size_t)((b * 16 + h) * S + s)) * 8192;
#pragma unroll
        for (int mt = 0; mt < 2; ++mt)
#pragma unroll
            for (int nt = 0; nt < 8; ++nt) {
                u16x4 v;
#pragma unroll
                for (int r = 0; r < 4; ++r) v[r] = f2bf(o[mt][nt][r]);
                *(u16x4*)(ob + (((qh * 2 + mt) * 8 + nt) * 64 + lane) * 4) = v;
            }
        if (l15 == 0) {
#pragma unroll
            for (int mt = 0; mt < 2; ++mt)
#pragma unroll
                for (int r = 0; r < 4; ++r) {
                    const int q = qbase + mt * 16 + l4 * 4 + r;
                    lsum[((size_t)((b * 16 + h) * 64 + q)) * S + s] = ol[mt][r];
                }
        }
    }
}

// ---------------- merge splits -> attn (B,K,NH*HD) bf16 -------------------
template <int S>
__global__ __launch_bounds__(256) void merge_kernel(
    const u16* __restrict__ Opart, const float* __restrict__ lsum, u16* __restrict__ attnb)
{
    const int wid = blockIdx.x * 4 + (threadIdx.x >> 6);   // (b*16+h)*2 + qh
    const int lane = threadIdx.x & 63;
    const int l15 = lane & 15, l4 = lane >> 4;
    const int qh = wid & 1, bh = wid >> 1;
    const int h = bh & 15, b = bh >> 4;

    float L = 0.f;
    {
        const float* lr = lsum + ((size_t)bh * 64 + qh * 32 + (lane & 31)) * S;
#pragma unroll
        for (int s2 = 0; s2 < S; ++s2) L += lr[s2];
    }
    const float invL = 1.0f / L;

    float acc[2][8][4];
#pragma unroll
    for (int mt = 0; mt < 2; ++mt)
#pragma unroll
        for (int nt = 0; nt < 8; ++nt)
#pragma unroll
            for (int r = 0; r < 4; ++r) acc[mt][nt][r] = 0.f;

    for (int s2 = 0; s2 < S; ++s2) {
        const u16* ob = Opart + ((size_t)(bh * S + s2)) * 8192;
#pragma unroll
        for (int mt = 0; mt < 2; ++mt)
#pragma unroll
            for (int nt = 0; nt < 8; ++nt) {
                u16x4 v = *(const u16x4*)(ob + (((qh * 2 + mt) * 8 + nt) * 64 + lane) * 4);
#pragma unroll
                for (int r = 0; r < 4; ++r) acc[mt][nt][r] += bf2f(v[r]);
            }
    }

#pragma unroll
    for (int mt = 0; mt < 2; ++mt)
#pragma unroll
        for (int r = 0; r < 4; ++r) {
            const float wl = __shfl(invL, mt * 16 + l4 * 4 + r);
            const int q = qh * 32 + mt * 16 + l4 * 4 + r;
            u16* dst = attnb + (size_t)(b * 64 + q) * 2048 + h * 128;
#pragma unroll
            for (int nt = 0; nt < 8; ++nt)
                dst[nt * 16 + l15] = f2bf(acc[mt][nt][r] * wl);
        }
}

// ---------------- launch ----------------
extern "C" void kernel_launch(void* const* d_in, const int* in_sizes, int n_in,
                              void* d_out, int out_size, void* d_ws, size_t ws_size,
                              hipStream_t stream)
{
    (void)in_sizes; (void)n_in; (void)out_size; (void)ws_size;
    const float* hs   = (const float*)d_in[0];
    const float* ctxk = (const float*)d_in[1];
    const float* ctxv = (const float*)d_in[2];
    const float* mask = (const float*)d_in[3];
    const float* cosT = (const float*)d_in[4];
    const float* sinT = (const float*)d_in[5];
    const float* wq   = (const float*)d_in[6];
    const float* wk   = (const float*)d_in[7];
    const float* wv   = (const float*)d_in[8];
    const float* wo   = (const float*)d_in[9];
    const float* qnw  = (const float*)d_in[10];
    const float* knw  = (const float*)d_in[11];

    const int S = 8;

    char* ws = (char*)d_ws;
    size_t off = 0;
    auto carve = [&](size_t bytes) -> void* {
        void* p = ws + off;
        off += (bytes + 255) & ~(size_t)255;
        return p;
    };
    u16*   Qb    = (u16*)carve((size_t)BB * NH * 64 * 128 * 2);         // 2.1 MB
    u16*   Kb    = (u16*)carve((size_t)BB * NKV * TTOT * 128 * 2);      // 34.1 MB
    u16*   VtG   = (u16*)carve((size_t)BB * NKV * TTOT * 128 * 2);      // 34.1 MB
    u16*   Opart = (u16*)carve((size_t)BB * NH * S * 8192 * 2);         // 16.8 MB
    float* lsumb = (float*)carve((size_t)BB * NH * 64 * S * 4);         // 0.26 MB
    u16*   attnb = (u16*)carve((size_t)512 * 2048 * 2);                 // 2.1 MB
    u16*   wob   = (u16*)carve((size_t)2048 * 2048 * 2);                // 8.4 MB
    u16*   knb   = (u16*)carve((size_t)BB * NKV * 64 * 128 * 2);        // 0.52 MB
    u16*   vnb   = (u16*)carve((size_t)BB * NKV * 64 * 128 * 2);        // 0.52 MB
    // ~99 MB. Time-multiplexed aliases (stream-ordered liveness):
    u16*   wqkvb = (u16*)Kb;     // bf16 qkv weights; dead before build_ctx
    float* qkvp  = (float*)VtG;  // qkv split-K partials; dead before build_ctx
    u16*   hsb   = (u16*)Opart;  // bf16 hs; dead before attn_partial
    float* outp  = (float*)Kb;   // out partials; Kb dead after attn_partial

    // 1) one fused cast of all weights + activations to bf16
    cast_all<<<5632, 256, 0, stream>>>(wq, wk, wv, wo, hs, wqkvb, wob, hsb);
    // 2) QKV projection (bf16, split-K x4, XCD swizzle)
    gemm_qkv_sk<<<1536, 256, 0, stream>>>(hsb, wqkvb, qkvp);
    // 3) fused reduce + RMSNorm/RoPE/cast -> Qb, k-noise, v-noise
    finalize_qkv<<<1536, 256, 0, stream>>>(qkvp, qnw, knw, cosT, sinT, Qb, knb, vnb);
    // 4) fused ctx K (kv-interleaved) + ctx V^T + noise scatter
    build_ctx<<<6208, 256, 0, stream>>>(ctxk, knw, cosT, sinT, ctxv, knb, vnb, Kb, VtG);
    // 5) flash attention + merge (attnb in bf16 for the out-proj)
    attn_partial<8><<<dim3(8, NKV, BB), 512, 0, stream>>>(Qb, Kb, VtG, mask, Opart, lsumb);
    merge_kernel<8><<<64, 256, 0, stream>>>(Opart, lsumb, attnb);
    // 6) output projection (bf16, split-K x4, XCD swizzle) -> reduce
    gemm_out_sk<<<1024, 256, 0, stream>>>(attnb, wob, outp);
    reduce4<<<1024, 256, 0, stream>>>(outp, (float*)d_out, (size_t)512 * 2048);
}

// Round 12
// 138.161 us; speedup vs baseline: 1.3121x; 1.0130x over previous
//
#include <hip/hip_runtime.h>

// ---------------- problem constants ----------------
#define BB   8
#define KQ   64
#define HDIM 2048
#define NH   16
#define NKV  4
#define HD   128
#define CTX  4096
#define TTOT 4160      // CTX + KQ
#define NTILES 65      // TTOT / 64
#define LOG2E 1.4426950408889634f
#define SCALE 0.08838834764831845f  // 1/sqrt(128)
#define QSCALE (SCALE * LOG2E)      // folded into Q; exp2-domain softmax
// |q.k| <= 128 after RMS-norm => |sc| <= 128*QSCALE = 16.33. Fixed softmax max.
#define MFIX 16.34f

typedef unsigned short u16;
typedef unsigned int   u32;
typedef __attribute__((ext_vector_type(8))) short  s16x8;   // bf16 storage
typedef __attribute__((ext_vector_type(4))) unsigned short u16x4;
typedef __attribute__((ext_vector_type(4))) float  f32x4;
typedef __bf16 bf16x8 __attribute__((ext_vector_type(8)));  // MFMA operand

__device__ __forceinline__ u16 f2bf(float f) {              // HW RNE cvt
    union { __bf16 h; u16 u; } v; v.h = (__bf16)f; return v.u;
}
__device__ __forceinline__ float bf2f(u16 u) {
    union { float f; u32 u; } v; v.u = ((u32)u) << 16;
    return v.f;
}
__device__ __forceinline__ u32 pack2(float a, float b) {
    return (u32)f2bf(a) | ((u32)f2bf(b) << 16);
}
__device__ __forceinline__ f32x4 mfma16(bf16x8 a, bf16x8 b, f32x4 c) {
    return __builtin_amdgcn_mfma_f32_16x16x32_bf16(a, b, c, 0, 0, 0);
}

// ---------------- fused f32 -> bf16 cast of all 5 tensors -----------------
__global__ __launch_bounds__(256) void cast_all(
    const float* __restrict__ wq, const float* __restrict__ wk,
    const float* __restrict__ wv, const float* __restrict__ wo,
    const float* __restrict__ hs,
    u16* __restrict__ wqkvb, u16* __restrict__ wob, u16* __restrict__ hsb)
{
    const int i = blockIdx.x * 256 + threadIdx.x;
    const float* src; u16* dst;
    if (i < 524288)       { src = wq + (size_t)i * 8;             dst = wqkvb + (size_t)i * 8; }
    else if (i < 655360)  { src = wk + (size_t)(i - 524288) * 8;  dst = wqkvb + (size_t)i * 8; }
    else if (i < 786432)  { src = wv + (size_t)(i - 655360) * 8;  dst = wqkvb + (size_t)i * 8; }
    else if (i < 1310720) { src = wo + (size_t)(i - 786432) * 8;  dst = wob + (size_t)(i - 786432) * 8; }
    else                  { src = hs + (size_t)(i - 1310720) * 8; dst = hsb + (size_t)(i - 1310720) * 8; }
    float4 a = *(const float4*)src;
    float4 b = *(const float4*)(src + 4);
    s16x8 v;
    v[0]=(short)f2bf(a.x); v[1]=(short)f2bf(a.y); v[2]=(short)f2bf(a.z); v[3]=(short)f2bf(a.w);
    v[4]=(short)f2bf(b.x); v[5]=(short)f2bf(b.y); v[6]=(short)f2bf(b.z); v[7]=(short)f2bf(b.w);
    *(s16x8*)dst = v;
}

// ---------------- 64x64-tile GEMM core, bf16 inputs (padded LDS) ----------
__device__ __forceinline__ void gemm64_body(
    const u16* __restrict__ Ab, const u16* __restrict__ Bb,
    float* __restrict__ Cb, const int ldc, const int ldk, const int Klen,
    u16* Ash, u16* Bsh)
{
    const int tid = threadIdx.x, lane = tid & 63;
    const int w = tid >> 6, wm = w >> 1, wn = w & 1;
    const int l15 = lane & 15, l4 = lane >> 4;
    const int srow = tid >> 2, scol = (tid & 3) * 16;

    f32x4 acc[2][2];
#pragma unroll
    for (int i = 0; i < 2; ++i)
#pragma unroll
        for (int j = 0; j < 2; ++j) acc[i][j] = (f32x4){0.f, 0.f, 0.f, 0.f};

    const u16* ap = Ab + (size_t)srow * ldk + scol;
    const u16* bp = Bb + (size_t)srow * ldk + scol;
    s16x8 ra0 = *(const s16x8*)ap, ra1 = *(const s16x8*)(ap + 8);
    s16x8 rb0 = *(const s16x8*)bp, rb1 = *(const s16x8*)(bp + 8);
    __builtin_amdgcn_sched_barrier(0);

    for (int k0 = 0; k0 < Klen; k0 += 64) {
        __syncthreads();
        *(s16x8*)(Ash + srow * 72 + scol)     = ra0;
        *(s16x8*)(Ash + srow * 72 + scol + 8) = ra1;
        *(s16x8*)(Bsh + srow * 72 + scol)     = rb0;
        *(s16x8*)(Bsh + srow * 72 + scol + 8) = rb1;
        __syncthreads();
        if (k0 + 64 < Klen) {
            const u16* ap2 = ap + k0 + 64;
            const u16* bp2 = bp + k0 + 64;
            ra0 = *(const s16x8*)ap2; ra1 = *(const s16x8*)(ap2 + 8);
            rb0 = *(const s16x8*)bp2; rb1 = *(const s16x8*)(bp2 + 8);
            __builtin_amdgcn_sched_barrier(0);
        }
#pragma unroll
        for (int ks = 0; ks < 2; ++ks) {
            bf16x8 am[2], bb[2];
#pragma unroll
            for (int i = 0; i < 2; ++i) {
                am[i] = *(const bf16x8*)(Ash + (wm * 32 + i * 16 + l15) * 72 + ks * 32 + l4 * 8);
                bb[i] = *(const bf16x8*)(Bsh + (wn * 32 + i * 16 + l15) * 72 + ks * 32 + l4 * 8);
            }
#pragma unroll
            for (int i = 0; i < 2; ++i)
#pragma unroll
                for (int j = 0; j < 2; ++j)
                    acc[i][j] = mfma16(am[i], bb[j], acc[i][j]);
        }
    }

    float* Cw = Cb + (size_t)(wm * 32) * ldc + wn * 32;
#pragma unroll
    for (int i = 0; i < 2; ++i)
#pragma unroll
        for (int j = 0; j < 2; ++j)
#pragma unroll
            for (int r = 0; r < 4; ++r)
                Cw[(size_t)(i * 16 + l4 * 4 + r) * ldc + j * 16 + l15] = acc[i][j][r];
}

// QKV projection, split-K x4, XCD-chunked swizzle. 1D grid 1536.
__global__ __launch_bounds__(256) void gemm_qkv_sk(
    const u16* __restrict__ hsb, const u16* __restrict__ wqkvb,
    float* __restrict__ qkvp)
{
    __shared__ __align__(16) u16 Ash[64 * 72];
    __shared__ __align__(16) u16 Bsh[64 * 72];
    const int wid = (blockIdx.x & 7) * 192 + (blockIdx.x >> 3);
    const int y = wid >> 5, rem = wid & 31, kc = rem >> 3, x = rem & 7;
    const int koff = kc * 512;
    const u16* Ab = hsb + (size_t)x * 64 * HDIM + koff;
    const u16* Bb = wqkvb + (size_t)y * 64 * HDIM + koff;
    float* Cb = qkvp + (size_t)kc * 512 * 3072 + (size_t)x * 64 * 3072 + y * 64;
    gemm64_body(Ab, Bb, Cb, 3072, HDIM, 512, Ash, Bsh);
}

// Output projection, split-K x4, XCD-chunked swizzle. 1D grid 1024.
__global__ __launch_bounds__(256) void gemm_out_sk(
    const u16* __restrict__ attnb, const u16* __restrict__ wob,
    float* __restrict__ outp)
{
    __shared__ __align__(16) u16 Ash[64 * 72];
    __shared__ __align__(16) u16 Bsh[64 * 72];
    const int wid = (blockIdx.x & 7) * 128 + (blockIdx.x >> 3);
    const int y = wid >> 5, rem = wid & 31, kc = rem >> 3, x = rem & 7;
    const int koff = kc * 512;
    const u16* Ab = attnb + (size_t)x * 64 * HDIM + koff;
    const u16* Bb = wob + (size_t)y * 64 * HDIM + koff;
    float* Cb = outp + (size_t)kc * 512 * 2048 + (size_t)x * 64 * 2048 + y * 64;
    gemm64_body(Ab, Bb, Cb, 2048, HDIM, 512, Ash, Bsh);
}

// sum 4 partial chunks -> out (float4 per thread), deterministic.
__global__ __launch_bounds__(256) void reduce4(
    const float* __restrict__ p, float* __restrict__ out, const size_t chunk)
{
    const size_t i = ((size_t)blockIdx.x * 256 + threadIdx.x) * 4;
    float4 a = *(const float4*)(p + i);
    float4 b = *(const float4*)(p + i + chunk);
    float4 c = *(const float4*)(p + i + 2 * chunk);
    float4 d = *(const float4*)(p + i + 3 * chunk);
    float4 r;
    r.x = (a.x + b.x) + (c.x + d.x);
    r.y = (a.y + b.y) + (c.y + d.y);
    r.z = (a.z + b.z) + (c.z + d.z);
    r.w = (a.w + b.w) + (c.w + d.w);
    *(float4*)(out + i) = r;
}

// ---------------- RMSNorm+RoPE on in-register values (half-wave) ----------
// cos/sin tables have duplicated halves: cos[pos][d+64]==cos[pos][d].
__device__ __forceinline__ void norm_rope_vals(
    float2 xa, float2 xb, const float* __restrict__ wgt,
    const float* __restrict__ cosT, const float* __restrict__ sinT,
    int pos, int j, float outScale, u16* __restrict__ dst)
{
    float ss = xa.x * xa.x + xa.y * xa.y + xb.x * xb.x + xb.y * xb.y;
#pragma unroll
    for (int m = 1; m < 32; m <<= 1) ss += __shfl_xor(ss, m);
    const float rr = rsqrtf(ss * (1.0f / 128.0f) + 1e-6f);
    float2 wa = *(const float2*)(wgt + 2 * j);
    float2 wb = *(const float2*)(wgt + 2 * j + 64);
    float2 ca = *(const float2*)(cosT + (size_t)pos * 128 + 2 * j);
    float2 sa = *(const float2*)(sinT + (size_t)pos * 128 + 2 * j);
    const float nax = xa.x * rr * wa.x, nay = xa.y * rr * wa.y;
    const float nbx = xb.x * rr * wb.x, nby = xb.y * rr * wb.y;
    const float lox = (nax * ca.x - nbx * sa.x) * outScale;
    const float loy = (nay * ca.y - nby * sa.y) * outScale;
    const float hix = (nbx * ca.x + nax * sa.x) * outScale;
    const float hiy = (nby * ca.y + nay * sa.y) * outScale;
    ((u32*)dst)[j]      = pack2(lox, loy);
    ((u32*)dst)[j + 32] = pack2(hix, hiy);
}

// ---------------- fused split-K reduce + RMSNorm/RoPE/cast ----------------
// slot: 0..15 q heads -> Qb; 16..19 k-noise -> knb; 20..23 v-noise -> vnb.
__global__ __launch_bounds__(256) void finalize_qkv(
    const float* __restrict__ qkvp, const float* __restrict__ qw,
    const float* __restrict__ kw, const float* __restrict__ cosT,
    const float* __restrict__ sinT,
    u16* __restrict__ Qb, u16* __restrict__ knb, u16* __restrict__ vnb)
{
    const int unit = blockIdx.x * 8 + (threadIdx.x >> 5);
    const int j = threadIdx.x & 31;
    const int slot = unit % 24, bq = unit / 24;
    const int b = bq >> 6, q = bq & 63;
    const int col0 = (slot < 16) ? slot * 128
                   : (slot < 20) ? 2048 + (slot - 16) * 128
                                 : 2560 + (slot - 20) * 128;
    const float* base = qkvp + (size_t)bq * 3072 + col0;

    float2 xa = {0.f, 0.f}, xb = {0.f, 0.f};
#pragma unroll
    for (int kc = 0; kc < 4; ++kc) {
        const float* p = base + (size_t)kc * 512 * 3072;
        float2 a = *(const float2*)(p + 2 * j);
        float2 c = *(const float2*)(p + 2 * j + 64);
        xa.x += a.x; xa.y += a.y; xb.x += c.x; xb.y += c.y;
    }

    if (slot < 16) {
        norm_rope_vals(xa, xb, qw, cosT, sinT, CTX + q, j, QSCALE,
                       Qb + ((size_t)((b * 16 + slot) * 64 + q)) * 128);
    } else if (slot < 20) {
        norm_rope_vals(xa, xb, kw, cosT, sinT, CTX + q, j, 1.0f,
                       knb + ((size_t)((b * 4 + (slot - 16)) * 64 + q)) * 128);
    } else {
        u16* dst = vnb + ((size_t)((b * 4 + (slot - 20)) * 64 + q)) * 128;
        ((u32*)dst)[j]      = pack2(xa.x, xa.y);
        ((u32*)dst)[j + 32] = pack2(xb.x, xb.y);
    }
}

// ---------------- ctx K build: norm+rope (kv x4 interleaved) + knb tail ---
// blocks [0,4096): half-wave per (b,pos). [4096,4128): knb -> Kb copy.
__global__ __launch_bounds__(256) void build_ctx_k(
    const float* __restrict__ ctxk, const float* __restrict__ kw,
    const float* __restrict__ cosT, const float* __restrict__ sinT,
    const u16* __restrict__ knb, u16* __restrict__ Kb)
{
    const int bid = blockIdx.x;
    if (bid < 4096) {
        const int unit = bid * 8 + (threadIdx.x >> 5);   // b*4096 + pos
        const int j = threadIdx.x & 31;
        const int b = unit >> 12, pos = unit & 4095;
        float2 ca = *(const float2*)(cosT + (size_t)pos * 128 + 2 * j);
        float2 sa = *(const float2*)(sinT + (size_t)pos * 128 + 2 * j);
        float2 wa = *(const float2*)(kw + 2 * j);
        float2 wb = *(const float2*)(kw + 2 * j + 64);
        const float* src0 = ctxk + (size_t)unit * 512;   // 4 kv rows of 128
        float2 xa[4], xb[4];
#pragma unroll
        for (int kv = 0; kv < 4; ++kv) {
            xa[kv] = *(const float2*)(src0 + kv * 128 + 2 * j);
            xb[kv] = *(const float2*)(src0 + kv * 128 + 2 * j + 64);
        }
        float ss[4];
#pragma unroll
        for (int kv = 0; kv < 4; ++kv)
            ss[kv] = xa[kv].x * xa[kv].x + xa[kv].y * xa[kv].y
                   + xb[kv].x * xb[kv].x + xb[kv].y * xb[kv].y;
#pragma unroll
        for (int m = 1; m < 32; m <<= 1) {
#pragma unroll
            for (int kv = 0; kv < 4; ++kv) ss[kv] += __shfl_xor(ss[kv], m);
        }
#pragma unroll
        for (int kv = 0; kv < 4; ++kv) {
            const float rr = rsqrtf(ss[kv] * (1.0f / 128.0f) + 1e-6f);
            const float nax = xa[kv].x * rr * wa.x, nay = xa[kv].y * rr * wa.y;
            const float nbx = xb[kv].x * rr * wb.x, nby = xb[kv].y * rr * wb.y;
            u16* dst = Kb + ((size_t)(b * 4 + kv) * TTOT + pos) * 128;
            ((u32*)dst)[j]      = pack2(nax * ca.x - nbx * sa.x, nay * ca.y - nby * sa.y);
            ((u32*)dst)[j + 32] = pack2(nbx * ca.x + nax * sa.x, nby * ca.y + nay * sa.y);
        }
    } else {
        const int idx = bid - 4096;   // b*4+kv
        const u16* src = knb + (size_t)idx * 64 * 128;
        u16* dst = Kb + ((size_t)idx * TTOT + 4096) * 128;
#pragma unroll
        for (int it = 0; it < 4; ++it) {
            const int e = (it * 256 + threadIdx.x) * 8;
            *(s16x8*)(dst + e) = *(const s16x8*)(src + e);
        }
    }
}

// ---------------- ctx V^T build: LDS-staged transpose + vnb tail ----------
// Round-11 lesson: the strided-read version compiled to 28 VGPR -> the 32
// per-thread 4B loads serialized (each ~900cy HBM latency exposed) -> the
// whole fused build_ctx plateaued at 2.1 TB/s. Here: phase 1 = fully
// coalesced float4 loads into LDS (8 independent loads/thread, few regs);
// phase 2 = conflict-free column reads from LDS -> bf16 -> 64B/thread
// contiguous global writes. blocks [0,2048): ctx tiles; [2048,2080): vnb^T.
__global__ __launch_bounds__(256) void build_ctx_v(
    const float* __restrict__ ctxv, const u16* __restrict__ vnb,
    u16* __restrict__ VtG)
{
    __shared__ __align__(16) float Vt[64 * 130];   // pad 2: col reads 2-way-free
    const int bid = blockIdx.x;
    if (bid < 2048) {
        const int pt = bid & 63, kv = (bid >> 6) & 3, b = bid >> 8;
        const int p0 = pt * 64;
        const float* src = ctxv + ((size_t)(b * 4096 + p0) * 4 + kv) * 128;
        // phase 1: 64 rows x 128 f32, coalesced (rows 2KB apart in global)
#pragma unroll
        for (int it = 0; it < 8; ++it) {
            const int g = it * 256 + threadIdx.x;     // float4 index
            const int row = g >> 5, c4 = (g & 31) * 4;
            *(float4*)(&Vt[row * 130 + c4]) = *(const float4*)(src + (size_t)row * 512 + c4);
        }
        __syncthreads();
        // phase 2: transpose out as bf16 d-rows
        const int d = threadIdx.x & 127, half = threadIdx.x >> 7;
        u16* dst = VtG + ((size_t)(b * 4 + kv) * 128 + d) * TTOT + p0 + half * 32;
#pragma unroll
        for (int q8 = 0; q8 < 4; ++q8) {
            s16x8 v;
#pragma unroll
            for (int je = 0; je < 8; ++je)
                v[je] = (short)f2bf(Vt[(half * 32 + q8 * 8 + je) * 130 + d]);
            *(s16x8*)(dst + q8 * 8) = v;
        }
    } else {
        const int idx = bid - 2048;   // b*4+kv
        const u16* src = vnb + (size_t)idx * 64 * 128;
        u16* dstb = VtG + (size_t)idx * 128 * TTOT + 4096;
        const int d = threadIdx.x & 127, qh = threadIdx.x >> 7;
        u16* dst = dstb + (size_t)d * TTOT + qh * 32;
#pragma unroll
        for (int q8 = 0; q8 < 4; ++q8) {
            s16x8 v;
#pragma unroll
            for (int je = 0; je < 8; ++je)
                v[je] = (short)src[(size_t)(qh * 32 + q8 * 8 + je) * 128 + d];
            *(s16x8*)(dst + q8 * 8) = v;
        }
    }
}

// ---------------- flash attention partial: pipelined double-buffer --------
template <int S>
__global__ __launch_bounds__(512, 2) void attn_partial(
    const u16* __restrict__ Qb, const u16* __restrict__ Kb, const u16* __restrict__ VtG,
    const float* __restrict__ mask, u16* __restrict__ Opart, float* __restrict__ lsum)
{
    __shared__ __align__(16) u16   Ksh[2][64 * 136];   // K [pos][d], padded
    __shared__ __align__(16) u16   Vsh[2][128 * 72];   // V^T [d][pos], padded
    __shared__ __align__(16) float Msh[2][64 * 68];    // mask*log2e - MFIX
    __shared__ __align__(16) u16   Psh[8][32 * 40];    // per-wave P chunk

    const int s = blockIdx.x, kv = blockIdx.y, b = blockIdx.z;
    const int tid = threadIdx.x, lane = tid & 63, w = tid >> 6;
    const int h = kv * 4 + (w >> 1);
    const int qh = w & 1, qbase = qh * 32;
    const int l15 = lane & 15, l4 = lane >> 4;
    const int t0 = (NTILES * s) / S, t1 = (NTILES * (s + 1)) / S;

    bf16x8 aq[2][4];
    {
        const u16* qb = Qb + ((size_t)((b * 16 + h) * 64 + qbase)) * 128;
#pragma unroll
        for (int mt = 0; mt < 2; ++mt)
#pragma unroll
            for (int ks = 0; ks < 4; ++ks)
                aq[mt][ks] = *(const bf16x8*)(qb + (mt * 16 + l15) * 128 + ks * 32 + l4 * 8);
    }

    bf16x8 bones;   // col-0 ones -> P row sums via MFMA
    {
        __bf16 e = (l15 == 0) ? (__bf16)1.0f : (__bf16)0.0f;
#pragma unroll
        for (int i = 0; i < 8; ++i) bones[i] = e;
    }

    f32x4 o[2][8], ol[2];
#pragma unroll
    for (int mt = 0; mt < 2; ++mt) {
        ol[mt] = (f32x4){0.f, 0.f, 0.f, 0.f};
#pragma unroll
        for (int nt = 0; nt < 8; ++nt) o[mt][nt] = (f32x4){0.f, 0.f, 0.f, 0.f};
    }

    const u16* Kbase = Kb + (size_t)(b * 4 + kv) * TTOT * 128;
    const u16* Vbase = VtG + (size_t)(b * 4 + kv) * 128 * TTOT;
    const float* mrow = mask + (size_t)b * 64 * TTOT;
    u16* P = Psh[w];

    const int kp = tid >> 4, kd8 = (tid & 15) * 8;   // K rows kp, kp+32
    const int vr = tid >> 3, vc8 = (tid & 7) * 8;    // V rows vr, vr+64
    const int mq_ = tid >> 3, mk8 = (tid & 7) * 8;   // mask row, col block

    s16x8 rk0, rk1, rv0, rv1;
    float4 rm0, rm1;

    auto ld = [&](int t) {
        const int p = t * 64;
        rk0 = *(const s16x8*)(Kbase + (size_t)(p + kp) * 128 + kd8);
        rk1 = *(const s16x8*)(Kbase + (size_t)(p + kp + 32) * 128 + kd8);
        rv0 = *(const s16x8*)(Vbase + (size_t)vr * TTOT + p + vc8);
        rv1 = *(const s16x8*)(Vbase + (size_t)(vr + 64) * TTOT + p + vc8);
        const float* mp = mrow + (size_t)mq_ * TTOT + p + mk8;
        rm0 = *(const float4*)mp;
        rm1 = *(const float4*)(mp + 4);
        __builtin_amdgcn_sched_barrier(0);   // pin load issue here
    };
    auto st = [&](int buf) {
        *(s16x8*)(Ksh[buf] + kp * 136 + kd8) = rk0;
        *(s16x8*)(Ksh[buf] + (kp + 32) * 136 + kd8) = rk1;
        *(s16x8*)(Vsh[buf] + vr * 72 + vc8) = rv0;
        *(s16x8*)(Vsh[buf] + (vr + 64) * 72 + vc8) = rv1;
        float* md = Msh[buf] + mq_ * 68 + mk8;
        md[0] = fmaf(rm0.x, LOG2E, -MFIX); md[1] = fmaf(rm0.y, LOG2E, -MFIX);
        md[2] = fmaf(rm0.z, LOG2E, -MFIX); md[3] = fmaf(rm0.w, LOG2E, -MFIX);
        md[4] = fmaf(rm1.x, LOG2E, -MFIX); md[5] = fmaf(rm1.y, LOG2E, -MFIX);
        md[6] = fmaf(rm1.z, LOG2E, -MFIX); md[7] = fmaf(rm1.w, LOG2E, -MFIX);
    };

    // prologue
    ld(t0);
    st(0);
    __syncthreads();
    if (t0 + 1 < t1) ld(t0 + 1);

    int cur = 0;
    for (int t = t0; t < t1; ++t) {
        // ---- compute tile t from buf[cur] ----
        f32x4 sc[2][4];
#pragma unroll
        for (int mt = 0; mt < 2; ++mt)
#pragma unroll
            for (int nt = 0; nt < 4; ++nt) sc[mt][nt] = (f32x4){0.f, 0.f, 0.f, 0.f};
        __builtin_amdgcn_s_setprio(1);
#pragma unroll
        for (int nt = 0; nt < 4; ++nt) {
#pragma unroll
            for (int ks = 0; ks < 4; ++ks) {
                bf16x8 bk = *(const bf16x8*)(Ksh[cur] + (nt * 16 + l15) * 136 + ks * 32 + l4 * 8);
                sc[0][nt] = mfma16(aq[0][ks], bk, sc[0][nt]);
                sc[1][nt] = mfma16(aq[1][ks], bk, sc[1][nt]);
            }
        }
        __builtin_amdgcn_s_setprio(0);

        // fixed-max softmax: p = exp2(sc + msh), msh = mask*log2e - MFIX
#pragma unroll
        for (int mt = 0; mt < 2; ++mt) {
#pragma unroll
            for (int r = 0; r < 4; ++r) {
                const int q = qbase + mt * 16 + l4 * 4 + r;
                const float* mq = Msh[cur] + q * 68 + l15;
                sc[mt][0][r] = exp2f(sc[mt][0][r] + mq[0]);
                sc[mt][1][r] = exp2f(sc[mt][1][r] + mq[16]);
                sc[mt][2][r] = exp2f(sc[mt][2][r] + mq[32]);
                sc[mt][3][r] = exp2f(sc[mt][3][r] + mq[48]);
            }
        }

        // O += P V ; l += P 1
#pragma unroll
        for (int ks = 0; ks < 2; ++ks) {
#pragma unroll
            for (int mt = 0; mt < 2; ++mt)
#pragma unroll
                for (int r = 0; r < 4; ++r) {
                    P[(mt * 16 + l4 * 4 + r) * 40 + l15]      = f2bf(sc[mt][ks * 2 + 0][r]);
                    P[(mt * 16 + l4 * 4 + r) * 40 + 16 + l15] = f2bf(sc[mt][ks * 2 + 1][r]);
                }
            bf16x8 ap0 = *(const bf16x8*)(P + (l15) * 40 + l4 * 8);
            bf16x8 ap1 = *(const bf16x8*)(P + (16 + l15) * 40 + l4 * 8);
            __builtin_amdgcn_s_setprio(1);
#pragma unroll
            for (int nt = 0; nt < 8; ++nt) {
                bf16x8 bv = *(const bf16x8*)(Vsh[cur] + (nt * 16 + l15) * 72 + ks * 32 + l4 * 8);
                o[0][nt] = mfma16(ap0, bv, o[0][nt]);
                o[1][nt] = mfma16(ap1, bv, o[1][nt]);
            }
            ol[0] = mfma16(ap0, bones, ol[0]);
            ol[1] = mfma16(ap1, bones, ol[1]);
            __builtin_amdgcn_s_setprio(0);
        }

        // ---- stage tile t+1 into buf[cur^1]; prefetch t+2 ----
        if (t + 1 < t1) st(cur ^ 1);      // waits vmcnt for ld(t+1) regs here
        __syncthreads();                  // vmcnt already 0: no drain cost
        if (t + 2 < t1) ld(t + 2);        // in flight across next compute
        cur ^= 1;
    }

    // coalesced epilogue: Opart chunk per (b,h,s) = [qh][mt][nt][lane][r] u16
    {
        u16* ob = Opart + ((size_t)((b * 16 + h) * S + s)) * 8192;
#pragma unroll
        for (int mt = 0; mt < 2; ++mt)
#pragma unroll
            for (int nt = 0; nt < 8; ++nt) {
                u16x4 v;
#pragma unroll
                for (int r = 0; r < 4; ++r) v[r] = f2bf(o[mt][nt][r]);
                *(u16x4*)(ob + (((qh * 2 + mt) * 8 + nt) * 64 + lane) * 4) = v;
            }
        if (l15 == 0) {
#pragma unroll
            for (int mt = 0; mt < 2; ++mt)
#pragma unroll
                for (int r = 0; r < 4; ++r) {
                    const int q = qbase + mt * 16 + l4 * 4 + r;
                    lsum[((size_t)((b * 16 + h) * 64 + q)) * S + s] = ol[mt][r];
                }
        }
    }
}

// ---------------- merge splits -> attn (B,K,NH*HD) bf16 -------------------
template <int S>
__global__ __launch_bounds__(256) void merge_kernel(
    const u16* __restrict__ Opart, const float* __restrict__ lsum, u16* __restrict__ attnb)
{
    const int wid = blockIdx.x * 4 + (threadIdx.x >> 6);   // (b*16+h)*2 + qh
    const int lane = threadIdx.x & 63;
    const int l15 = lane & 15, l4 = lane >> 4;
    const int qh = wid & 1, bh = wid >> 1;
    const int h = bh & 15, b = bh >> 4;

    float L = 0.f;
    {
        const float* lr = lsum + ((size_t)bh * 64 + qh * 32 + (lane & 31)) * S;
#pragma unroll
        for (int s2 = 0; s2 < S; ++s2) L += lr[s2];
    }
    const float invL = 1.0f / L;

    float acc[2][8][4];
#pragma unroll
    for (int mt = 0; mt < 2; ++mt)
#pragma unroll
        for (int nt = 0; nt < 8; ++nt)
#pragma unroll
            for (int r = 0; r < 4; ++r) acc[mt][nt][r] = 0.f;

    for (int s2 = 0; s2 < S; ++s2) {
        const u16* ob = Opart + ((size_t)(bh * S + s2)) * 8192;
#pragma unroll
        for (int mt = 0; mt < 2; ++mt)
#pragma unroll
            for (int nt = 0; nt < 8; ++nt) {
                u16x4 v = *(const u16x4*)(ob + (((qh * 2 + mt) * 8 + nt) * 64 + lane) * 4);
#pragma unroll
                for (int r = 0; r < 4; ++r) acc[mt][nt][r] += bf2f(v[r]);
            }
    }

#pragma unroll
    for (int mt = 0; mt < 2; ++mt)
#pragma unroll
        for (int r = 0; r < 4; ++r) {
            const float wl = __shfl(invL, mt * 16 + l4 * 4 + r);
            const int q = qh * 32 + mt * 16 + l4 * 4 + r;
            u16* dst = attnb + (size_t)(b * 64 + q) * 2048 + h * 128;
#pragma unroll
            for (int nt = 0; nt < 8; ++nt)
                dst[nt * 16 + l15] = f2bf(acc[mt][nt][r] * wl);
        }
}

// ---------------- launch ----------------
extern "C" void kernel_launch(void* const* d_in, const int* in_sizes, int n_in,
                              void* d_out, int out_size, void* d_ws, size_t ws_size,
                              hipStream_t stream)
{
    (void)in_sizes; (void)n_in; (void)out_size; (void)ws_size;
    const float* hs   = (const float*)d_in[0];
    const float* ctxk = (const float*)d_in[1];
    const float* ctxv = (const float*)d_in[2];
    const float* mask = (const float*)d_in[3];
    const float* cosT = (const float*)d_in[4];
    const float* sinT = (const float*)d_in[5];
    const float* wq   = (const float*)d_in[6];
    const float* wk   = (const float*)d_in[7];
    const float* wv   = (const float*)d_in[8];
    const float* wo   = (const float*)d_in[9];
    const float* qnw  = (const float*)d_in[10];
    const float* knw  = (const float*)d_in[11];

    const int S = 8;

    char* ws = (char*)d_ws;
    size_t off = 0;
    auto carve = [&](size_t bytes) -> void* {
        void* p = ws + off;
        off += (bytes + 255) & ~(size_t)255;
        return p;
    };
    u16*   Qb    = (u16*)carve((size_t)BB * NH * 64 * 128 * 2);         // 2.1 MB
    u16*   Kb    = (u16*)carve((size_t)BB * NKV * TTOT * 128 * 2);      // 34.1 MB
    u16*   VtG   = (u16*)carve((size_t)BB * NKV * TTOT * 128 * 2);      // 34.1 MB
    u16*   Opart = (u16*)carve((size_t)BB * NH * S * 8192 * 2);         // 16.8 MB
    float* lsumb = (float*)carve((size_t)BB * NH * 64 * S * 4);         // 0.26 MB
    u16*   attnb = (u16*)carve((size_t)512 * 2048 * 2);                 // 2.1 MB
    u16*   wob   = (u16*)carve((size_t)2048 * 2048 * 2);                // 8.4 MB
    u16*   knb   = (u16*)carve((size_t)BB * NKV * 64 * 128 * 2);        // 0.52 MB
    u16*   vnb   = (u16*)carve((size_t)BB * NKV * 64 * 128 * 2);        // 0.52 MB
    // ~99 MB. Time-multiplexed aliases (stream-ordered liveness):
    u16*   wqkvb = (u16*)Kb;     // bf16 qkv weights; dead before build_ctx_k
    float* qkvp  = (float*)VtG;  // qkv split-K partials; dead before build_ctx_v
    u16*   hsb   = (u16*)Opart;  // bf16 hs; dead before attn_partial
    float* outp  = (float*)Kb;   // out partials; Kb dead after attn_partial

    // 1) one fused cast of all weights + activations to bf16
    cast_all<<<5632, 256, 0, stream>>>(wq, wk, wv, wo, hs, wqkvb, wob, hsb);
    // 2) QKV projection (bf16, split-K x4, XCD swizzle)
    gemm_qkv_sk<<<1536, 256, 0, stream>>>(hsb, wqkvb, qkvp);
    // 3) fused reduce + RMSNorm/RoPE/cast -> Qb, k-noise, v-noise
    finalize_qkv<<<1536, 256, 0, stream>>>(qkvp, qnw, knw, cosT, sinT, Qb, knb, vnb);
    // 4) ctx K (norm+rope) and ctx V^T (LDS-staged transpose), split kernels
    build_ctx_k<<<4128, 256, 0, stream>>>(ctxk, knw, cosT, sinT, knb, Kb);
    build_ctx_v<<<2080, 256, 0, stream>>>(ctxv, vnb, VtG);
    // 5) flash attention + merge (attnb in bf16 for the out-proj)
    attn_partial<8><<<dim3(8, NKV, BB), 512, 0, stream>>>(Qb, Kb, VtG, mask, Opart, lsumb);
    merge_kernel<8><<<64, 256, 0, stream>>>(Opart, lsumb, attnb);
    // 6) output projection (bf16, split-K x4, XCD swizzle) -> reduce
    gemm_out_sk<<<1024, 256, 0, stream>>>(attnb, wob, outp);
    reduce4<<<1024, 256, 0, stream>>>(outp, (float*)d_out, (size_t)512 * 2048);
}